// Round 5
// baseline (482.405 us; speedup 1.0000x reference)
//
#include <hip/hip_runtime.h>
#include <math.h>

#define HWn   3136
#define Cn    256
#define KCPB  49          // 3136/64 k-chunks per batch image
#define NCHUNK 3136       // 64 batches * 49 chunks
#define INV_M (1.0f/200704.0f)
#define EPSc  1e-5f

typedef __attribute__((ext_vector_type(4))) float f32x4;
typedef __attribute__((ext_vector_type(8))) short s16x8;
typedef __attribute__((ext_vector_type(4))) unsigned short u16x4;

static __device__ __forceinline__ unsigned short f2bf(float f) {
  unsigned int u = __builtin_bit_cast(unsigned int, f);
  u = (u + 0x7fffu + ((u >> 16) & 1u)) >> 16;   // RNE
  return (unsigned short)u;
}

// Software grid barrier (all blocks co-resident; device-scope fence+atomics).
static __device__ __forceinline__ void grid_sync(unsigned int* bar, unsigned int target) {
  __syncthreads();                       // drains all waves' vmem (waitcnt before s_barrier)
  if (threadIdx.x == 0) {
    __threadfence();                     // release: L2 writeback (cross-XCD visibility)
    atomicAdd(bar, 1u);
    while (__hip_atomic_load(bar, __ATOMIC_RELAXED, __HIP_MEMORY_SCOPE_AGENT) < target)
      __builtin_amdgcn_s_sleep(2);
  }
  __syncthreads();
  __threadfence();                       // acquire: invalidate L1/L2 before reading peers' data
}

// ---------------------------------------------------------------------------
// Kernel 1: partial Gram (raw, uncentered) + per-part channel sums (Sp).
// Double-buffered LDS, T14 split (loads -> MFMA -> cvt+write -> barrier).
// ---------------------------------------------------------------------------
__global__ __launch_bounds__(1024) void k_gram(const float* __restrict__ X,
                                               float* __restrict__ Gp,
                                               float* __restrict__ Sp,
                                               int nparts) {
  __shared__ __align__(16) unsigned short lds[2][256 * 64];
  const int t = threadIdx.x, p = blockIdx.x;
  const int w = t >> 6, l = t & 63, a = l & 15, g = l >> 4;
  const int swzA = (a & 7) << 3;
  const int crow = t >> 4, sg = t & 15;

  f32x4 acc[16];
#pragma unroll
  for (int j = 0; j < 16; ++j) acc[j] = (f32x4){0.f, 0.f, 0.f, 0.f};
  float sum4[4] = {0.f, 0.f, 0.f, 0.f};
  float vx[16];

  const int start = (int)(((long)NCHUNK * p) / nparts);
  const int end   = (int)(((long)NCHUNK * (p + 1)) / nparts);

#define G_LOADS(CH)                                                           \
  {                                                                           \
    const int b_ = (CH) / KCPB, kc_ = (CH) % KCPB;                            \
    const float* xb_ = X + (long)b_ * Cn * HWn + kc_ * 64;                    \
    _Pragma("unroll")                                                         \
    for (int p4 = 0; p4 < 4; ++p4) {                                          \
      const float4 v = *(const float4*)(xb_ + (long)(p4 * 64 + crow) * HWn + sg * 4); \
      vx[p4 * 4 + 0] = v.x; vx[p4 * 4 + 1] = v.y;                             \
      vx[p4 * 4 + 2] = v.z; vx[p4 * 4 + 3] = v.w;                             \
    }                                                                         \
  }

#define G_CVTWR(BUF)                                                          \
  {                                                                           \
    _Pragma("unroll")                                                         \
    for (int p4 = 0; p4 < 4; ++p4) {                                          \
      const int c_ = p4 * 64 + crow;                                          \
      sum4[p4] += (vx[p4 * 4 + 0] + vx[p4 * 4 + 1])                           \
                + (vx[p4 * 4 + 2] + vx[p4 * 4 + 3]);                          \
      u16x4 h;                                                                \
      h.x = f2bf(vx[p4 * 4 + 0]); h.y = f2bf(vx[p4 * 4 + 1]);                 \
      h.z = f2bf(vx[p4 * 4 + 2]); h.w = f2bf(vx[p4 * 4 + 3]);                 \
      *(u16x4*)(&lds[BUF][0] + ((c_ * 64 + sg * 4) ^ ((c_ & 7) << 3))) = h;   \
    }                                                                         \
  }

  G_LOADS(start);
  G_CVTWR(0);
  __syncthreads();

  for (int ch = start; ch < end; ++ch) {
    const int cur = (ch - start) & 1;
    if (ch + 1 < end) G_LOADS(ch + 1);
    const unsigned short* tile = &lds[cur][0];
#pragma unroll
    for (int kk = 0; kk < 64; kk += 32) {
      const s16x8 fw = *(const s16x8*)(tile + (((w * 16 + a) * 64 + kk + g * 8) ^ swzA));
#pragma unroll
      for (int j = 0; j < 16; ++j) {
        const s16x8 fj = *(const s16x8*)(tile + (((j * 16 + a) * 64 + kk + g * 8) ^ swzA));
        acc[j] = __builtin_amdgcn_mfma_f32_16x16x32_bf16(fw, fj, acc[j], 0, 0, 0);
      }
    }
    if (ch + 1 < end) G_CVTWR(cur ^ 1);
    __syncthreads();
  }
#undef G_LOADS
#undef G_CVTWR

  float* gout = Gp + (long)p * 65536;
#pragma unroll
  for (int j = 0; j < 16; ++j)
#pragma unroll
    for (int r = 0; r < 4; ++r)
      gout[(16 * w + 4 * g + r) * 256 + 16 * j + a] = acc[j][r];

#pragma unroll
  for (int p4 = 0; p4 < 4; ++p4) {
    float s = sum4[p4];
    s += __shfl_xor(s, 1);
    s += __shfl_xor(s, 2);
    s += __shfl_xor(s, 4);
    s += __shfl_xor(s, 8);
    if (a == 0) Sp[(long)p * 256 + p4 * 64 + w * 4 + g] = s;
  }
}

// ---------------------------------------------------------------------------
// Kernel 2: reduce partials -> Sigma row per block; diag/meansum export;
// zeroes the grid-barrier counter for the fused NS kernel.
// ---------------------------------------------------------------------------
__global__ __launch_bounds__(1024) void k_reduce(const float* __restrict__ Gp,
                                                 const float* __restrict__ Sp,
                                                 float* __restrict__ Sigma,
                                                 float* __restrict__ diag,
                                                 float* __restrict__ meansum,
                                                 unsigned int* __restrict__ bar,
                                                 int nparts) {
  __shared__ float redA[4][256];
  __shared__ float msh[256];
  __shared__ __align__(16) float redB[16][256];
  const int t = threadIdx.x, j = blockIdx.x;
  const int c = t & 255, g = t >> 8;

  // ---- Phase A: channel sums ----
  {
    float s = 0.f;
    const int pa0 = (nparts * g) >> 2, pa1 = (nparts * (g + 1)) >> 2;
    for (int p = pa0; p < pa1; ++p) s += Sp[(long)p * 256 + c];
    redA[g][c] = s;
  }
  __syncthreads();
  if (g == 0) msh[c] = (redA[0][c] + redA[1][c]) + (redA[2][c] + redA[3][c]);

  // ---- Phase B: Gram column reduction, float4 slabs ----
  {
    const int c4 = (t & 63) * 4, sl = t >> 6;
    const int pb0 = (nparts * sl) >> 4, pb1 = (nparts * (sl + 1)) >> 4;
    const float* gp = Gp + (long)pb0 * 65536 + (long)j * 256 + c4;
    f32x4 s4 = (f32x4){0.f, 0.f, 0.f, 0.f};
    for (int p = pb0; p < pb1; ++p) { s4 += *(const f32x4*)gp; gp += 65536; }
    *(f32x4*)&redB[sl][c4] = s4;
  }
  __syncthreads();

  if (t < 256) {
    float t0 = 0.f, t1 = 0.f;
#pragma unroll
    for (int sl = 0; sl < 16; sl += 2) { t0 += redB[sl][t]; t1 += redB[sl + 1][t]; }
    const float tot = t0 + t1;
    const float mc = msh[t] * INV_M;
    const float mj = msh[j] * INV_M;
    const float sig = tot * INV_M - mj * mc + ((j == t) ? EPSc : 0.f);
    Sigma[(long)j * 256 + t] = sig;
    if (t == j) diag[j] = sig;
    if (j == 0) {
      meansum[t] = msh[t];
      if (t == 0)
        __hip_atomic_store(bar, 0u, __ATOMIC_RELAXED, __HIP_MEMORY_SCOPE_SYSTEM);
    }
  }
}

// ---------------------------------------------------------------------------
// Kernel 3 (fused): trace -> 10 Newton-Schulz iterations -> A=sqrt(rTr)*rot*P
// -> Abf(bf16) + bias. 64 blocks x 1024 threads, persistent, grid barriers.
// Iter 0 (P=I) computed in closed form: P1 = 1.5 I - 0.5 rTr Sigma.
// ---------------------------------------------------------------------------
__global__ __launch_bounds__(1024) void k_ns_fused(const float* __restrict__ Sig,
                                                   float* __restrict__ P0,
                                                   float* __restrict__ P1,
                                                   const float* __restrict__ diag,
                                                   const float* __restrict__ rot,
                                                   const float* __restrict__ meansum,
                                                   unsigned int* __restrict__ bar,
                                                   unsigned short* __restrict__ Abf,
                                                   float* __restrict__ bias) {
  __shared__ __align__(16) float PT[256][4];       // A-panel transposed [k][r]
  __shared__ __align__(16) float red[4][256][4];   // [kh][c][r]
  __shared__ float trs[256];
  const int t = threadIdx.x, c = t & 255, kh = t >> 8, k0 = kh * 64;
  const int r0 = blockIdx.x * 4;

  // ---- per-block trace (identical reduction order in every block) ----
  if (t < 256) trs[t] = diag[t];
  __syncthreads();
  for (int st = 128; st > 0; st >>= 1) {
    if (t < st) trs[t] += trs[t + st];
    __syncthreads();
  }
  const float rTr = 1.0f / trs[0];

  // ---- iteration 0 closed form ----
  {
    const int row = r0 + kh;
    const float sv = Sig[(long)row * 256 + c];
    P1[(long)row * 256 + c] = ((row == c) ? 1.5f : 0.f) - 0.5f * rTr * sv;
  }
  unsigned int tgt = 64;
  grid_sync(bar, tgt); tgt += 64;

  f32x4 acc;

#define NS_PHASE(BPTR)                                                        \
  {                                                                           \
    acc = (f32x4){0.f, 0.f, 0.f, 0.f};                                        \
    const float* Bb = (BPTR) + (long)k0 * 256 + c;                            \
    _Pragma("unroll 8")                                                       \
    for (int kk = 0; kk < 64; ++kk) {                                         \
      const float b = Bb[(long)kk * 256];                                     \
      const f32x4 a4 = *(const f32x4*)&PT[k0 + kk][0];                        \
      acc += a4 * b;                                                          \
    }                                                                         \
    *(f32x4*)&red[kh][c][0] = acc;                                            \
    __syncthreads();                                                          \
  }

#define NS_COMBINE()                                                          \
  {                                                                           \
    const f32x4 vs = (*(const f32x4*)&red[0][c][0] + *(const f32x4*)&red[1][c][0]) \
                   + (*(const f32x4*)&red[2][c][0] + *(const f32x4*)&red[3][c][0]); \
    if (kh == 0) *(f32x4*)&PT[c][0] = vs;                                     \
    __syncthreads();                                                          \
  }

  for (int it = 1; it < 10; ++it) {
    const float* Ps = (it & 1) ? P1 : P0;
    float* Pd = (it & 1) ? P0 : P1;

    PT[c][kh] = Ps[(long)(r0 + kh) * 256 + c];
    __syncthreads();

    NS_PHASE(Ps);    // t1 = panel(P) * P
    NS_COMBINE();
    NS_PHASE(Ps);    // t2 = t1 * P
    NS_COMBINE();
    NS_PHASE(Sig);   // t3 = t2 * Sigma

    const float t3 = ((red[0][c][kh] + red[1][c][kh]) + (red[2][c][kh] + red[3][c][kh]));
    const float pr = Ps[(long)(r0 + kh) * 256 + c];
    Pd[(long)(r0 + kh) * 256 + c] = 1.5f * pr - 0.5f * rTr * t3;

    grid_sync(bar, tgt); tgt += 64;
  }
#undef NS_PHASE
#undef NS_COMBINE

  // ---- makeA: A = sqrt(rTr) * (rot_panel x P0); Abf bf16; bias = A*mean ----
  PT[c][kh] = rot[(long)(r0 + kh) * 256 + c];
  __syncthreads();
  {
    acc = (f32x4){0.f, 0.f, 0.f, 0.f};
    const float* Bb = P0 + (long)k0 * 256 + c;
#pragma unroll 8
    for (int kk = 0; kk < 64; ++kk) {
      const float b = Bb[(long)kk * 256];
      const f32x4 a4 = *(const f32x4*)&PT[k0 + kk][0];
      acc += a4 * b;
    }
    *(f32x4*)&red[kh][c][0] = acc;
  }
  __syncthreads();
  const float s2 = sqrtf(rTr);
  if (t < 256) {
    f32x4 av = (*(const f32x4*)&red[0][t][0] + *(const f32x4*)&red[1][t][0])
             + (*(const f32x4*)&red[2][t][0] + *(const f32x4*)&red[3][t][0]);
    av *= s2;
#pragma unroll
    for (int i = 0; i < 4; ++i) Abf[(r0 + i) * 256 + t] = f2bf(av[i]);
    const float mc = meansum[t] * INV_M;
    *(f32x4*)&PT[t][0] = av * mc;
  }
  __syncthreads();
  for (int st = 128; st > 0; st >>= 1) {
    if (t < st) {
      const f32x4 v = *(const f32x4*)&PT[t][0] + *(const f32x4*)&PT[t + st][0];
      *(f32x4*)&PT[t][0] = v;
    }
    __syncthreads();
  }
  if (t == 0) {
    const f32x4 bv = *(const f32x4*)&PT[0][0];
#pragma unroll
    for (int i = 0; i < 4; ++i) bias[r0 + i] = bv[i];
  }
}

// ---------------------------------------------------------------------------
// Kernel 4: out = A*x - bias. 512 blocks (64 b x 8 strips of 6-7 chunks).
// Swapped MFMA operands -> D rows = s -> nontemporal float4 stores.
// ---------------------------------------------------------------------------
__global__ __launch_bounds__(1024) void k_apply(const float* __restrict__ X,
                                                const unsigned short* __restrict__ Abf,
                                                const float* __restrict__ bias,
                                                float* __restrict__ out) {
  __shared__ __align__(16) unsigned short lds[2][64 * 256];
  const int t = threadIdx.x, w = t >> 6, l = t & 63, a = l & 15, g = l >> 4;
  const int bid = blockIdx.x;
  const int b = bid >> 3, strip = bid & 7;
  const int ch0 = (49 * strip) >> 3, ch1 = (49 * (strip + 1)) >> 3;

  const int d = 16 * w + a;
  s16x8 af[8];
#pragma unroll
  for (int kk8 = 0; kk8 < 8; ++kk8)
    af[kk8] = *(const s16x8*)(Abf + d * 256 + kk8 * 32 + g * 8);
  const float bd = bias[d];

  const float* xbase = X + (long)b * Cn * HWn;
  float* obase = out + (long)b * Cn * HWn;
  float vx[16];

#define A_LOADS(CH)                                                           \
  {                                                                           \
    const int s0_ = (CH) * 64;                                                \
    _Pragma("unroll")                                                         \
    for (int p4 = 0; p4 < 4; ++p4) {                                          \
      const int c4_ = p4 * 16 + w;                                            \
      const float* xp_ = xbase + (long)(c4_ * 4) * HWn + s0_ + l;             \
      vx[p4 * 4 + 0] = xp_[0];                                                \
      vx[p4 * 4 + 1] = xp_[HWn];                                              \
      vx[p4 * 4 + 2] = xp_[2 * HWn];                                          \
      vx[p4 * 4 + 3] = xp_[3 * HWn];                                          \
    }                                                                         \
  }

#define A_CVTWR(BUF)                                                          \
  {                                                                           \
    _Pragma("unroll")                                                         \
    for (int p4 = 0; p4 < 4; ++p4) {                                          \
      const int c4_ = p4 * 16 + w;                                            \
      u16x4 h;                                                                \
      h.x = f2bf(vx[p4 * 4 + 0]); h.y = f2bf(vx[p4 * 4 + 1]);                 \
      h.z = f2bf(vx[p4 * 4 + 2]); h.w = f2bf(vx[p4 * 4 + 3]);                 \
      *(u16x4*)(&lds[BUF][0] + ((l * 256 + c4_ * 4) ^ ((l & 7) << 3))) = h;   \
    }                                                                         \
  }

  A_LOADS(ch0);
  A_CVTWR(0);
  __syncthreads();

  for (int ch = ch0; ch < ch1; ++ch) {
    const int cur = (ch - ch0) & 1;
    if (ch + 1 < ch1) A_LOADS(ch + 1);

    const unsigned short* tile = &lds[cur][0];
    f32x4 acc[4];
#pragma unroll
    for (int st = 0; st < 4; ++st) acc[st] = (f32x4){0.f, 0.f, 0.f, 0.f};
#pragma unroll
    for (int kk8 = 0; kk8 < 8; ++kk8) {
#pragma unroll
      for (int st = 0; st < 4; ++st) {
        const s16x8 xf = *(const s16x8*)(tile + (((st * 16 + a) * 256 + kk8 * 32 + g * 8) ^ ((a & 7) << 3)));
        acc[st] = __builtin_amdgcn_mfma_f32_16x16x32_bf16(xf, af[kk8], acc[st], 0, 0, 0);
      }
    }
    const int s0 = ch * 64;
#pragma unroll
    for (int st = 0; st < 4; ++st) {
      const f32x4 o = acc[st] - bd;
      __builtin_nontemporal_store(o, (f32x4*)(obase + (long)d * HWn + s0 + st * 16 + 4 * g));
    }

    if (ch + 1 < ch1) A_CVTWR(cur ^ 1);
    __syncthreads();
  }
#undef A_LOADS
#undef A_CVTWR
}

// ---------------------------------------------------------------------------
extern "C" void kernel_launch(void* const* d_in, const int* in_sizes, int n_in,
                              void* d_out, int out_size, void* d_ws, size_t ws_size,
                              hipStream_t stream) {
  const float* X = (const float*)d_in[0];
  const float* rot = (const float*)d_in[1];
  float* out = (float*)d_out;

  auto need = [](int np) -> size_t {
    return (size_t)4 * ((size_t)np * 65536 + (size_t)np * 256 + 3 * 65536
                        + 256 + 256 + 256 + 16)
         + (size_t)2 * 65536;
  };
  int nparts = 256;
  while (nparts > 4 && need(nparts) > ws_size) nparts >>= 1;

  float* w = (float*)d_ws;
  float* Gp = w;       w += (size_t)nparts * 65536;
  float* Sp = w;       w += (size_t)nparts * 256;
  float* Sigma = w;    w += 65536;
  float* P0 = w;       w += 65536;
  float* P1 = w;       w += 65536;
  float* diag = w;     w += 256;
  float* meansum = w;  w += 256;
  float* bias = w;     w += 256;
  unsigned int* bar = (unsigned int*)w;  w += 16;
  unsigned short* Abf = (unsigned short*)w;

  k_gram<<<dim3(nparts), dim3(1024), 0, stream>>>(X, Gp, Sp, nparts);
  k_reduce<<<dim3(256), dim3(1024), 0, stream>>>(Gp, Sp, Sigma, diag, meansum, bar, nparts);
  k_ns_fused<<<dim3(64), dim3(1024), 0, stream>>>(Sigma, P0, P1, diag, rot, meansum, bar, Abf, bias);
  k_apply<<<dim3(512), dim3(1024), 0, stream>>>(X, Abf, bias, out);
}

// Round 6
// 297.550 us; speedup vs baseline: 1.6213x; 1.6213x over previous
//
#include <hip/hip_runtime.h>
#include <math.h>

#define HWn   3136
#define Cn    256
#define KCPB  49          // 3136/64 k-chunks per batch image
#define NCHUNK 3136       // 64 batches * 49 chunks
#define INV_M (1.0f/200704.0f)
#define EPSc  1e-5f

typedef __attribute__((ext_vector_type(4))) float f32x4;
typedef __attribute__((ext_vector_type(8))) short s16x8;
typedef __attribute__((ext_vector_type(4))) unsigned short u16x4;

static __device__ __forceinline__ unsigned short f2bf(float f) {
  unsigned int u = __builtin_bit_cast(unsigned int, f);
  u = (u + 0x7fffu + ((u >> 16) & 1u)) >> 16;   // RNE
  return (unsigned short)u;
}

// HW packed f32x2 -> bf16x2 (RNE). Non-volatile: scheduler may move it.
static __device__ __forceinline__ unsigned int cvt_pk_bf16(float lo, float hi) {
  unsigned int r;
  asm("v_cvt_pk_bf16_f32 %0, %1, %2" : "=v"(r) : "v"(lo), "v"(hi));
  return r;
}

// ---------------------------------------------------------------------------
// Kernel 1: partial Gram (raw, uncentered) + per-part channel sums (Sp).
// Double-buffered LDS, T14 split (loads -> MFMA -> cvt+write -> barrier).
// ---------------------------------------------------------------------------
__global__ __launch_bounds__(1024) void k_gram(const float* __restrict__ X,
                                               float* __restrict__ Gp,
                                               float* __restrict__ Sp,
                                               int nparts) {
  __shared__ __align__(16) unsigned short lds[2][256 * 64];
  const int t = threadIdx.x, p = blockIdx.x;
  const int w = t >> 6, l = t & 63, a = l & 15, g = l >> 4;
  const int swzA = (a & 7) << 3;
  const int crow = t >> 4, sg = t & 15;

  f32x4 acc[16];
#pragma unroll
  for (int j = 0; j < 16; ++j) acc[j] = (f32x4){0.f, 0.f, 0.f, 0.f};
  float sum4[4] = {0.f, 0.f, 0.f, 0.f};
  float vx[16];

  const int start = (int)(((long)NCHUNK * p) / nparts);
  const int end   = (int)(((long)NCHUNK * (p + 1)) / nparts);

#define G_LOADS(CH)                                                           \
  {                                                                           \
    const int b_ = (CH) / KCPB, kc_ = (CH) % KCPB;                            \
    const float* xb_ = X + (long)b_ * Cn * HWn + kc_ * 64;                    \
    _Pragma("unroll")                                                         \
    for (int p4 = 0; p4 < 4; ++p4) {                                          \
      const float4 v = *(const float4*)(xb_ + (long)(p4 * 64 + crow) * HWn + sg * 4); \
      vx[p4 * 4 + 0] = v.x; vx[p4 * 4 + 1] = v.y;                             \
      vx[p4 * 4 + 2] = v.z; vx[p4 * 4 + 3] = v.w;                             \
    }                                                                         \
  }

#define G_CVTWR(BUF)                                                          \
  {                                                                           \
    _Pragma("unroll")                                                         \
    for (int p4 = 0; p4 < 4; ++p4) {                                          \
      const int c_ = p4 * 64 + crow;                                          \
      sum4[p4] += (vx[p4 * 4 + 0] + vx[p4 * 4 + 1])                           \
                + (vx[p4 * 4 + 2] + vx[p4 * 4 + 3]);                          \
      uint2 hh;                                                               \
      hh.x = cvt_pk_bf16(vx[p4 * 4 + 0], vx[p4 * 4 + 1]);                     \
      hh.y = cvt_pk_bf16(vx[p4 * 4 + 2], vx[p4 * 4 + 3]);                     \
      *(uint2*)(&lds[BUF][0] + ((c_ * 64 + sg * 4) ^ ((c_ & 7) << 3))) = hh;  \
    }                                                                         \
  }

  G_LOADS(start);
  G_CVTWR(0);
  __syncthreads();

  for (int ch = start; ch < end; ++ch) {
    const int cur = (ch - start) & 1;
    if (ch + 1 < end) G_LOADS(ch + 1);
    const unsigned short* tile = &lds[cur][0];
#pragma unroll
    for (int kk = 0; kk < 64; kk += 32) {
      const s16x8 fw = *(const s16x8*)(tile + (((w * 16 + a) * 64 + kk + g * 8) ^ swzA));
#pragma unroll
      for (int j = 0; j < 16; ++j) {
        const s16x8 fj = *(const s16x8*)(tile + (((j * 16 + a) * 64 + kk + g * 8) ^ swzA));
        acc[j] = __builtin_amdgcn_mfma_f32_16x16x32_bf16(fw, fj, acc[j], 0, 0, 0);
      }
    }
    if (ch + 1 < end) G_CVTWR(cur ^ 1);
    __syncthreads();
  }
#undef G_LOADS
#undef G_CVTWR

  float* gout = Gp + (long)p * 65536;
#pragma unroll
  for (int j = 0; j < 16; ++j)
#pragma unroll
    for (int r = 0; r < 4; ++r)
      gout[(16 * w + 4 * g + r) * 256 + 16 * j + a] = acc[j][r];

#pragma unroll
  for (int p4 = 0; p4 < 4; ++p4) {
    float s = sum4[p4];
    s += __shfl_xor(s, 1);
    s += __shfl_xor(s, 2);
    s += __shfl_xor(s, 4);
    s += __shfl_xor(s, 8);
    if (a == 0) Sp[(long)p * 256 + p4 * 64 + w * 4 + g] = s;
  }
}

// ---------------------------------------------------------------------------
// Kernel 2: reduce partials -> Sigma row per block; diag/meansum export.
// ---------------------------------------------------------------------------
__global__ __launch_bounds__(1024) void k_reduce(const float* __restrict__ Gp,
                                                 const float* __restrict__ Sp,
                                                 float* __restrict__ Sigma,
                                                 float* __restrict__ diag,
                                                 float* __restrict__ meansum,
                                                 int nparts) {
  __shared__ float redA[4][256];
  __shared__ float msh[256];
  __shared__ __align__(16) float redB[16][256];
  const int t = threadIdx.x, j = blockIdx.x;
  const int c = t & 255, g = t >> 8;

  // ---- Phase A: channel sums ----
  {
    float s = 0.f;
    const int pa0 = (nparts * g) >> 2, pa1 = (nparts * (g + 1)) >> 2;
    for (int p = pa0; p < pa1; ++p) s += Sp[(long)p * 256 + c];
    redA[g][c] = s;
  }
  __syncthreads();
  if (g == 0) msh[c] = (redA[0][c] + redA[1][c]) + (redA[2][c] + redA[3][c]);

  // ---- Phase B: Gram column reduction, float4 slabs ----
  {
    const int c4 = (t & 63) * 4, sl = t >> 6;
    const int pb0 = (nparts * sl) >> 4, pb1 = (nparts * (sl + 1)) >> 4;
    const float* gp = Gp + (long)pb0 * 65536 + (long)j * 256 + c4;
    f32x4 s4 = (f32x4){0.f, 0.f, 0.f, 0.f};
    for (int p = pb0; p < pb1; ++p) { s4 += *(const f32x4*)gp; gp += 65536; }
    *(f32x4*)&redB[sl][c4] = s4;
  }
  __syncthreads();

  if (t < 256) {
    float t0 = 0.f, t1 = 0.f;
#pragma unroll
    for (int sl = 0; sl < 16; sl += 2) { t0 += redB[sl][t]; t1 += redB[sl + 1][t]; }
    const float tot = t0 + t1;
    const float mc = msh[t] * INV_M;
    const float mj = msh[j] * INV_M;
    const float sig = tot * INV_M - mj * mc + ((j == t) ? EPSc : 0.f);
    Sigma[(long)j * 256 + t] = sig;
    if (t == j) diag[j] = sig;
    if (j == 0) meansum[t] = msh[t];
  }
}

// ---------------------------------------------------------------------------
// Kernel 3: iteration 0 closed form (P = I): P1 = 1.5 I - 0.5 rTr Sigma.
// Per-block trace from diag (identical order); block 0 exports scal.
// ---------------------------------------------------------------------------
__global__ __launch_bounds__(1024) void k_it0(const float* __restrict__ Sig,
                                              const float* __restrict__ diag,
                                              float* __restrict__ P1,
                                              float* __restrict__ scal) {
  __shared__ float trs[256];
  const int t = threadIdx.x, c = t & 255, kh = t >> 8;
  const int row = blockIdx.x * 4 + kh;
  if (t < 256) trs[t] = diag[t];
  __syncthreads();
  for (int st = 128; st > 0; st >>= 1) {
    if (t < st) trs[t] += trs[t + st];
    __syncthreads();
  }
  const float tr = trs[0];
  const float rTr = 1.0f / tr;
  P1[(long)row * 256 + c] = ((row == c) ? 1.5f : 0.f) - 0.5f * rTr * Sig[(long)row * 256 + c];
  if (blockIdx.x == 0 && t == 0) {
    scal[0] = tr;
    scal[1] = rTr;
    scal[2] = sqrtf(rTr);
  }
}

// ---------------------------------------------------------------------------
// Kernel 4 (x9): one Newton-Schulz step, fp32.
// 64 blocks x 1024 threads: 4 rows/block, 256 cols, split-K x4.
// ---------------------------------------------------------------------------
__global__ __launch_bounds__(1024) void k_ns(const float* __restrict__ Ps,
                                             float* __restrict__ Pd,
                                             const float* __restrict__ Sig,
                                             const float* __restrict__ scal) {
  __shared__ __align__(16) float PT[256][4];       // A-panel transposed [k][r]
  __shared__ __align__(16) float red[4][256][4];   // [kh][c][r]
  const int t = threadIdx.x, c = t & 255, kh = t >> 8, k0 = kh * 64;
  const int r0 = blockIdx.x * 4;

  PT[c][kh] = Ps[(r0 + kh) * 256 + c];
  __syncthreads();

  f32x4 acc;

#define NS_PHASE(BPTR)                                                        \
  {                                                                           \
    acc = (f32x4){0.f, 0.f, 0.f, 0.f};                                        \
    const float* Bb = (BPTR) + (long)k0 * 256 + c;                            \
    _Pragma("unroll 8")                                                       \
    for (int kk = 0; kk < 64; ++kk) {                                         \
      const float b = Bb[(long)kk * 256];                                     \
      const f32x4 a4 = *(const f32x4*)&PT[k0 + kk][0];                        \
      acc += a4 * b;                                                          \
    }                                                                         \
    *(f32x4*)&red[kh][c][0] = acc;                                            \
    __syncthreads();                                                          \
  }

#define NS_COMBINE()                                                          \
  {                                                                           \
    const f32x4 vs = (*(const f32x4*)&red[0][c][0] + *(const f32x4*)&red[1][c][0]) \
                   + (*(const f32x4*)&red[2][c][0] + *(const f32x4*)&red[3][c][0]); \
    if (kh == 0) *(f32x4*)&PT[c][0] = vs;                                     \
    __syncthreads();                                                          \
  }

  NS_PHASE(Ps);    // t1 = panel(P) * P
  NS_COMBINE();
  NS_PHASE(Ps);    // t2 = t1 * P
  NS_COMBINE();
  NS_PHASE(Sig);   // t3 = t2 * Sigma

  const float rTr = scal[1];
  const float t3 = ((red[0][c][kh] + red[1][c][kh]) + (red[2][c][kh] + red[3][c][kh]));
  const float pr = Ps[(r0 + kh) * 256 + c];
  Pd[(r0 + kh) * 256 + c] = 1.5f * pr - 0.5f * rTr * t3;
#undef NS_PHASE
#undef NS_COMBINE
}

// ---------------------------------------------------------------------------
// Kernel 5: A = sqrt(rTr) * (rot * P) -> bf16; bias = A * mean.
// ---------------------------------------------------------------------------
__global__ void k_makeA(const float* __restrict__ rot, const float* __restrict__ P,
                        const float* __restrict__ scal, const float* __restrict__ meansum,
                        unsigned short* __restrict__ Abf, float* __restrict__ bias) {
  __shared__ float Rw[8][256];
  __shared__ float Tw[8][256];
  const int r0 = blockIdx.x * 8, c = threadIdx.x;
#pragma unroll
  for (int r = 0; r < 8; ++r) Rw[r][c] = rot[(r0 + r) * 256 + c];
  __syncthreads();
  float t[8];
#pragma unroll
  for (int r = 0; r < 8; ++r) t[r] = 0.f;
  for (int k = 0; k < 256; ++k) {
    const float pv = P[k * 256 + c];
#pragma unroll
    for (int r = 0; r < 8; ++r) t[r] += Rw[r][k] * pv;
  }
  const float s = scal[2];
  const float mc = meansum[c] * INV_M;
#pragma unroll
  for (int r = 0; r < 8; ++r) {
    const float av = t[r] * s;
    Abf[(r0 + r) * 256 + c] = f2bf(av);
    Tw[r][c] = av * mc;
  }
  __syncthreads();
  for (int st = 128; st > 0; st >>= 1) {
    if (c < st) {
#pragma unroll
      for (int r = 0; r < 8; ++r) Tw[r][c] += Tw[r][c + st];
    }
    __syncthreads();
  }
  if (c == 0) {
#pragma unroll
    for (int r = 0; r < 8; ++r) bias[r0 + r] = Tw[r][0];
  }
}

// ---------------------------------------------------------------------------
// Kernel 6: out = A*x - bias. 512 blocks (64 b x 8 strips of 6-7 chunks).
// Swapped MFMA operands -> D rows = s -> nontemporal float4 stores.
// ---------------------------------------------------------------------------
__global__ __launch_bounds__(1024) void k_apply(const float* __restrict__ X,
                                                const unsigned short* __restrict__ Abf,
                                                const float* __restrict__ bias,
                                                float* __restrict__ out) {
  __shared__ __align__(16) unsigned short lds[2][64 * 256];
  const int t = threadIdx.x, w = t >> 6, l = t & 63, a = l & 15, g = l >> 4;
  const int bid = blockIdx.x;
  const int b = bid >> 3, strip = bid & 7;
  const int ch0 = (49 * strip) >> 3, ch1 = (49 * (strip + 1)) >> 3;

  const int d = 16 * w + a;
  s16x8 af[8];
#pragma unroll
  for (int kk8 = 0; kk8 < 8; ++kk8)
    af[kk8] = *(const s16x8*)(Abf + d * 256 + kk8 * 32 + g * 8);
  const float bd = bias[d];

  const float* xbase = X + (long)b * Cn * HWn;
  float* obase = out + (long)b * Cn * HWn;
  float vx[16];

#define A_LOADS(CH)                                                           \
  {                                                                           \
    const int s0_ = (CH) * 64;                                                \
    _Pragma("unroll")                                                         \
    for (int p4 = 0; p4 < 4; ++p4) {                                          \
      const int c4_ = p4 * 16 + w;                                            \
      const float* xp_ = xbase + (long)(c4_ * 4) * HWn + s0_ + l;             \
      vx[p4 * 4 + 0] = xp_[0];                                                \
      vx[p4 * 4 + 1] = xp_[HWn];                                              \
      vx[p4 * 4 + 2] = xp_[2 * HWn];                                          \
      vx[p4 * 4 + 3] = xp_[3 * HWn];                                          \
    }                                                                         \
  }

#define A_CVTWR(BUF)                                                          \
  {                                                                           \
    _Pragma("unroll")                                                         \
    for (int p4 = 0; p4 < 4; ++p4) {                                          \
      const int c4_ = p4 * 16 + w;                                            \
      uint2 hh;                                                               \
      hh.x = cvt_pk_bf16(vx[p4 * 4 + 0], vx[p4 * 4 + 1]);                     \
      hh.y = cvt_pk_bf16(vx[p4 * 4 + 2], vx[p4 * 4 + 3]);                     \
      *(uint2*)(&lds[BUF][0] + ((l * 256 + c4_ * 4) ^ ((l & 7) << 3))) = hh;  \
    }                                                                         \
  }

  A_LOADS(ch0);
  A_CVTWR(0);
  __syncthreads();

  for (int ch = ch0; ch < ch1; ++ch) {
    const int cur = (ch - ch0) & 1;
    if (ch + 1 < ch1) A_LOADS(ch + 1);

    const unsigned short* tile = &lds[cur][0];
    f32x4 acc[4];
#pragma unroll
    for (int st = 0; st < 4; ++st) acc[st] = (f32x4){0.f, 0.f, 0.f, 0.f};
#pragma unroll
    for (int kk8 = 0; kk8 < 8; ++kk8) {
#pragma unroll
      for (int st = 0; st < 4; ++st) {
        const s16x8 xf = *(const s16x8*)(tile + (((st * 16 + a) * 256 + kk8 * 32 + g * 8) ^ ((a & 7) << 3)));
        acc[st] = __builtin_amdgcn_mfma_f32_16x16x32_bf16(xf, af[kk8], acc[st], 0, 0, 0);
      }
    }
    const int s0 = ch * 64;
#pragma unroll
    for (int st = 0; st < 4; ++st) {
      const f32x4 o = acc[st] - bd;
      __builtin_nontemporal_store(o, (f32x4*)(obase + (long)d * HWn + s0 + st * 16 + 4 * g));
    }

    if (ch + 1 < ch1) A_CVTWR(cur ^ 1);
    __syncthreads();
  }
#undef A_LOADS
#undef A_CVTWR
}

// ---------------------------------------------------------------------------
extern "C" void kernel_launch(void* const* d_in, const int* in_sizes, int n_in,
                              void* d_out, int out_size, void* d_ws, size_t ws_size,
                              hipStream_t stream) {
  const float* X = (const float*)d_in[0];
  const float* rot = (const float*)d_in[1];
  float* out = (float*)d_out;

  auto need = [](int np) -> size_t {
    return (size_t)4 * ((size_t)np * 65536 + (size_t)np * 256 + 3 * 65536
                        + 256 + 256 + 16 + 256)
         + (size_t)2 * 65536;
  };
  int nparts = 128;
  while (nparts > 4 && need(nparts) > ws_size) nparts >>= 1;

  float* w = (float*)d_ws;
  float* Gp = w;       w += (size_t)nparts * 65536;
  float* Sp = w;       w += (size_t)nparts * 256;
  float* Sigma = w;    w += 65536;
  float* P0 = w;       w += 65536;
  float* P1 = w;       w += 65536;
  float* diag = w;     w += 256;
  float* meansum = w;  w += 256;
  float* scal = w;     w += 16;
  float* bias = w;     w += 256;
  unsigned short* Abf = (unsigned short*)w;

  k_gram<<<dim3(nparts), dim3(1024), 0, stream>>>(X, Gp, Sp, nparts);
  k_reduce<<<dim3(256), dim3(1024), 0, stream>>>(Gp, Sp, Sigma, diag, meansum, nparts);
  k_it0<<<dim3(64), dim3(1024), 0, stream>>>(Sigma, diag, P1, scal);
  float* ps = P1;
  float* pd = P0;
  for (int i = 0; i < 9; ++i) {
    k_ns<<<dim3(64), dim3(1024), 0, stream>>>(ps, pd, Sigma, scal);
    float* tmp = ps; ps = pd; pd = tmp;
  }
  k_makeA<<<dim3(32), dim3(256), 0, stream>>>(rot, ps, scal, meansum, Abf, bias);
  k_apply<<<dim3(512), dim3(1024), 0, stream>>>(X, Abf, bias, out);
}

// Round 7
// 285.007 us; speedup vs baseline: 1.6926x; 1.0440x over previous
//
#include <hip/hip_runtime.h>
#include <math.h>

#define HWn   3136
#define Cn    256
#define KCPB  49          // 3136/64 k-chunks per batch image
#define NCHUNK 3136       // 64 batches * 49 chunks
#define INV_M (1.0f/200704.0f)
#define EPSc  1e-5f

typedef __attribute__((ext_vector_type(4))) float f32x4;
typedef __attribute__((ext_vector_type(8))) short s16x8;
typedef __attribute__((ext_vector_type(4))) unsigned short u16x4;

static __device__ __forceinline__ unsigned short f2bf(float f) {
  unsigned int u = __builtin_bit_cast(unsigned int, f);
  u = (u + 0x7fffu + ((u >> 16) & 1u)) >> 16;   // RNE
  return (unsigned short)u;
}

// HW packed f32x2 -> bf16x2 (RNE).
static __device__ __forceinline__ unsigned int cvt_pk_bf16(float lo, float hi) {
  unsigned int r;
  asm("v_cvt_pk_bf16_f32 %0, %1, %2" : "=v"(r) : "v"(lo), "v"(hi));
  return r;
}

// ---------------------------------------------------------------------------
// Kernel 1: partial Gram (raw, uncentered) + per-part channel sums (Sp)
// + per-part Gram-diagonal partial sum (Dp, for fused trace computation).
// Double-buffered LDS, T14 split. Gp stores nontemporal (protect L3 for X).
// ---------------------------------------------------------------------------
__global__ __launch_bounds__(1024) void k_gram(const float* __restrict__ X,
                                               float* __restrict__ Gp,
                                               float* __restrict__ Sp,
                                               float* __restrict__ Dp,
                                               int nparts) {
  __shared__ __align__(16) unsigned short lds[2][256 * 64];
  const int t = threadIdx.x, p = blockIdx.x;
  const int w = t >> 6, l = t & 63, a = l & 15, g = l >> 4;
  const int swzA = (a & 7) << 3;
  const int crow = t >> 4, sg = t & 15;

  f32x4 acc[16];
#pragma unroll
  for (int j = 0; j < 16; ++j) acc[j] = (f32x4){0.f, 0.f, 0.f, 0.f};
  float sum4[4] = {0.f, 0.f, 0.f, 0.f};
  float vx[16];

  const int start = (int)(((long)NCHUNK * p) / nparts);
  const int end   = (int)(((long)NCHUNK * (p + 1)) / nparts);

#define G_LOADS(CH)                                                           \
  {                                                                           \
    const int b_ = (CH) / KCPB, kc_ = (CH) % KCPB;                            \
    const float* xb_ = X + (long)b_ * Cn * HWn + kc_ * 64;                    \
    _Pragma("unroll")                                                         \
    for (int p4 = 0; p4 < 4; ++p4) {                                          \
      const float4 v = *(const float4*)(xb_ + (long)(p4 * 64 + crow) * HWn + sg * 4); \
      vx[p4 * 4 + 0] = v.x; vx[p4 * 4 + 1] = v.y;                             \
      vx[p4 * 4 + 2] = v.z; vx[p4 * 4 + 3] = v.w;                             \
    }                                                                         \
  }

#define G_CVTWR(BUF)                                                          \
  {                                                                           \
    _Pragma("unroll")                                                         \
    for (int p4 = 0; p4 < 4; ++p4) {                                          \
      const int c_ = p4 * 64 + crow;                                          \
      sum4[p4] += (vx[p4 * 4 + 0] + vx[p4 * 4 + 1])                           \
                + (vx[p4 * 4 + 2] + vx[p4 * 4 + 3]);                          \
      uint2 hh;                                                               \
      hh.x = cvt_pk_bf16(vx[p4 * 4 + 0], vx[p4 * 4 + 1]);                     \
      hh.y = cvt_pk_bf16(vx[p4 * 4 + 2], vx[p4 * 4 + 3]);                     \
      *(uint2*)(&lds[BUF][0] + ((c_ * 64 + sg * 4) ^ ((c_ & 7) << 3))) = hh;  \
    }                                                                         \
  }

  G_LOADS(start);
  G_CVTWR(0);
  __syncthreads();

  for (int ch = start; ch < end; ++ch) {
    const int cur = (ch - start) & 1;
    if (ch + 1 < end) G_LOADS(ch + 1);
    const unsigned short* tile = &lds[cur][0];
#pragma unroll
    for (int kk = 0; kk < 64; kk += 32) {
      const s16x8 fw = *(const s16x8*)(tile + (((w * 16 + a) * 64 + kk + g * 8) ^ swzA));
#pragma unroll
      for (int j = 0; j < 16; ++j) {
        const s16x8 fj = *(const s16x8*)(tile + (((j * 16 + a) * 64 + kk + g * 8) ^ swzA));
        acc[j] = __builtin_amdgcn_mfma_f32_16x16x32_bf16(fw, fj, acc[j], 0, 0, 0);
      }
    }
    if (ch + 1 < end) G_CVTWR(cur ^ 1);
    __syncthreads();
  }
#undef G_LOADS
#undef G_CVTWR

  // ---- write partial Gram (nontemporal: read exactly once by k_reduce) ----
  float* gout = Gp + (long)p * 65536;
#pragma unroll
  for (int j = 0; j < 16; ++j)
#pragma unroll
    for (int r = 0; r < 4; ++r)
      __builtin_nontemporal_store(acc[j][r],
          gout + (16 * w + 4 * g + r) * 256 + 16 * j + a);

  // ---- channel sums: reduce over the 16 sg-lanes, store per (p,chan) ----
#pragma unroll
  for (int p4 = 0; p4 < 4; ++p4) {
    float s = sum4[p4];
    s += __shfl_xor(s, 1);
    s += __shfl_xor(s, 2);
    s += __shfl_xor(s, 4);
    s += __shfl_xor(s, 8);
    if (a == 0) Sp[(long)p * 256 + p4 * 64 + w * 4 + g] = s;
  }

  // ---- Gram diagonal partial: row 16w+4g+r == col 16w+a  (static indices) --
  {
    float dsum = 0.f;
#pragma unroll
    for (int j = 0; j < 16; ++j) {
      if (j == w && (a >> 2) == g) {
#pragma unroll
        for (int r = 0; r < 4; ++r)
          if ((a & 3) == r) dsum = acc[j][r];
      }
    }
#pragma unroll
    for (int off = 1; off < 64; off <<= 1) dsum += __shfl_xor(dsum, off);
    float* lf = (float*)lds;
    if (l == 0) lf[w] = dsum;
    __syncthreads();
    if (t == 0) {
      float d = 0.f;
#pragma unroll
      for (int ww = 0; ww < 16; ++ww) d += lf[ww];
      Dp[p] = d;
    }
  }
}

// ---------------------------------------------------------------------------
// Kernel 2: reduce partials -> Sigma row per block; fused iteration-0:
// every block computes trace (identical order) -> rTr -> P1 row.
// Block 0 exports meansum + scal.
// ---------------------------------------------------------------------------
__global__ __launch_bounds__(1024) void k_reduce(const float* __restrict__ Gp,
                                                 const float* __restrict__ Sp,
                                                 const float* __restrict__ Dp,
                                                 float* __restrict__ Sigma,
                                                 float* __restrict__ P1,
                                                 float* __restrict__ meansum,
                                                 float* __restrict__ scal,
                                                 int nparts) {
  __shared__ float redA[4][256];
  __shared__ float msh[256];
  __shared__ float scrD[256];
  __shared__ float scrM[256];
  __shared__ __align__(16) float redB[16][256];
  const int t = threadIdx.x, j = blockIdx.x;
  const int c = t & 255, g = t >> 8;

  // ---- Phase A: channel sums ----
  {
    float s = 0.f;
    const int pa0 = (nparts * g) >> 2, pa1 = (nparts * (g + 1)) >> 2;
    for (int p = pa0; p < pa1; ++p) s += Sp[(long)p * 256 + c];
    redA[g][c] = s;
  }
  __syncthreads();
  if (g == 0) msh[c] = (redA[0][c] + redA[1][c]) + (redA[2][c] + redA[3][c]);
  __syncthreads();

  // ---- trace inputs: Gram-diag partials + mean^2 ----
  if (t < 256) {
    scrD[t] = (t < nparts) ? Dp[t] : 0.f;
    const float mc = msh[t] * INV_M;
    scrM[t] = mc * mc;
  }
  __syncthreads();
  for (int st = 128; st > 0; st >>= 1) {
    if (t < st) { scrD[t] += scrD[t + st]; scrM[t] += scrM[t + st]; }
    __syncthreads();
  }
  const float tr = scrD[0] * INV_M - scrM[0] + 256.f * EPSc;
  const float rTr = 1.0f / tr;

  // ---- Phase B: Gram column reduction, nontemporal float4 slabs ----
  {
    const int c4 = (t & 63) * 4, sl = t >> 6;
    const int pb0 = (nparts * sl) >> 4, pb1 = (nparts * (sl + 1)) >> 4;
    const float* gp = Gp + (long)pb0 * 65536 + (long)j * 256 + c4;
    f32x4 s4 = (f32x4){0.f, 0.f, 0.f, 0.f};
    for (int p = pb0; p < pb1; ++p) {
      s4 += __builtin_nontemporal_load((const f32x4*)gp);
      gp += 65536;
    }
    *(f32x4*)&redB[sl][c4] = s4;
  }
  __syncthreads();

  if (t < 256) {
    float t0 = 0.f, t1 = 0.f;
#pragma unroll
    for (int sl = 0; sl < 16; sl += 2) { t0 += redB[sl][t]; t1 += redB[sl + 1][t]; }
    const float tot = t0 + t1;
    const float mc = msh[t] * INV_M;
    const float mj = msh[j] * INV_M;
    const float sig = tot * INV_M - mj * mc + ((j == t) ? EPSc : 0.f);
    Sigma[(long)j * 256 + t] = sig;
    // fused iteration 0 (P = I):  P1 = 1.5 I - 0.5 rTr Sigma
    P1[(long)j * 256 + t] = ((j == t) ? 1.5f : 0.f) - 0.5f * rTr * sig;
    if (j == 0) {
      meansum[t] = msh[t];
      if (t == 0) { scal[0] = tr; scal[1] = rTr; scal[2] = sqrtf(rTr); }
    }
  }
}

// ---------------------------------------------------------------------------
// Kernel 3 (x8): one Newton-Schulz step, fp32.
// 64 blocks x 1024 threads: 4 rows/block, 256 cols, split-K x4.
// ---------------------------------------------------------------------------
__global__ __launch_bounds__(1024) void k_ns(const float* __restrict__ Ps,
                                             float* __restrict__ Pd,
                                             const float* __restrict__ Sig,
                                             const float* __restrict__ scal) {
  __shared__ __align__(16) float PT[256][4];       // A-panel transposed [k][r]
  __shared__ __align__(16) float red[4][256][4];   // [kh][c][r]
  const int t = threadIdx.x, c = t & 255, kh = t >> 8, k0 = kh * 64;
  const int r0 = blockIdx.x * 4;

  PT[c][kh] = Ps[(r0 + kh) * 256 + c];
  __syncthreads();

  f32x4 acc;

#define NS_PHASE(BPTR)                                                        \
  {                                                                           \
    acc = (f32x4){0.f, 0.f, 0.f, 0.f};                                        \
    const float* Bb = (BPTR) + (long)k0 * 256 + c;                            \
    _Pragma("unroll 8")                                                       \
    for (int kk = 0; kk < 64; ++kk) {                                         \
      const float b = Bb[(long)kk * 256];                                     \
      const f32x4 a4 = *(const f32x4*)&PT[k0 + kk][0];                        \
      acc += a4 * b;                                                          \
    }                                                                         \
    *(f32x4*)&red[kh][c][0] = acc;                                            \
    __syncthreads();                                                          \
  }

#define NS_COMBINE()                                                          \
  {                                                                           \
    const f32x4 vs = (*(const f32x4*)&red[0][c][0] + *(const f32x4*)&red[1][c][0]) \
                   + (*(const f32x4*)&red[2][c][0] + *(const f32x4*)&red[3][c][0]); \
    if (kh == 0) *(f32x4*)&PT[c][0] = vs;                                     \
    __syncthreads();                                                          \
  }

  NS_PHASE(Ps);    // t1 = panel(P) * P
  NS_COMBINE();
  NS_PHASE(Ps);    // t2 = t1 * P
  NS_COMBINE();
  NS_PHASE(Sig);   // t3 = t2 * Sigma

  const float rTr = scal[1];
  const float t3 = ((red[0][c][kh] + red[1][c][kh]) + (red[2][c][kh] + red[3][c][kh]));
  const float pr = Ps[(r0 + kh) * 256 + c];
  Pd[(r0 + kh) * 256 + c] = 1.5f * pr - 0.5f * rTr * t3;
}

// ---------------------------------------------------------------------------
// Kernel 4: fused last NS step + makeA:
// A = sqrt(rTr) * rot * P10 = sqrt(rTr) * (1.5*(rot*P9) - 0.5*rTr*(((rot*P9)*P9)*P9)*Sigma)
// 64 blocks x 1024, 4 chained panel phases. Also bias = A * mean.
// ---------------------------------------------------------------------------
__global__ __launch_bounds__(1024) void k_ns_makeA(const float* __restrict__ Ps,
                                                   const float* __restrict__ Sig,
                                                   const float* __restrict__ rot,
                                                   const float* __restrict__ scal,
                                                   const float* __restrict__ meansum,
                                                   unsigned short* __restrict__ Abf,
                                                   float* __restrict__ bias) {
  __shared__ __align__(16) float PT[256][4];
  __shared__ __align__(16) float red[4][256][4];
  __shared__ float Tw[4][256];
  const int t = threadIdx.x, c = t & 255, kh = t >> 8, k0 = kh * 64;
  const int r0 = blockIdx.x * 4;

  PT[c][kh] = rot[(r0 + kh) * 256 + c];
  __syncthreads();

  f32x4 acc;

  NS_PHASE(Ps);    // T1 = rot_panel * P9
  NS_COMBINE();
  const float t1 = PT[c][kh];          // own element of T1 (row kh, col c)
  NS_PHASE(Ps);    // T2 = T1 * P9
  NS_COMBINE();
  NS_PHASE(Ps);    // T3 = T2 * P9
  NS_COMBINE();
  NS_PHASE(Sig);   // T4 = T3 * Sigma

  const float rTr = scal[1];
  const float sq = scal[2];
  const float t4 = (red[0][c][kh] + red[1][c][kh]) + (red[2][c][kh] + red[3][c][kh]);
  const float av = sq * (1.5f * t1 - 0.5f * rTr * t4);
  Abf[(r0 + kh) * 256 + c] = f2bf(av);
  const float mc = meansum[c] * INV_M;
  Tw[kh][c] = av * mc;
  __syncthreads();
  for (int st = 128; st > 0; st >>= 1) {
    if (c < st) Tw[kh][c] += Tw[kh][c + st];
    __syncthreads();
  }
  if (c == 0) bias[r0 + kh] = Tw[kh][0];
#undef NS_PHASE
#undef NS_COMBINE
}

// ---------------------------------------------------------------------------
// Kernel 5: out = A*x - bias. 512 blocks (64 b x 8 strips of 6-7 chunks).
// Swapped MFMA operands -> D rows = s -> nontemporal float4 stores.
// ---------------------------------------------------------------------------
__global__ __launch_bounds__(1024) void k_apply(const float* __restrict__ X,
                                                const unsigned short* __restrict__ Abf,
                                                const float* __restrict__ bias,
                                                float* __restrict__ out) {
  __shared__ __align__(16) unsigned short lds[2][64 * 256];
  const int t = threadIdx.x, w = t >> 6, l = t & 63, a = l & 15, g = l >> 4;
  const int bid = blockIdx.x;
  const int b = bid >> 3, strip = bid & 7;
  const int ch0 = (49 * strip) >> 3, ch1 = (49 * (strip + 1)) >> 3;

  const int d = 16 * w + a;
  s16x8 af[8];
#pragma unroll
  for (int kk8 = 0; kk8 < 8; ++kk8)
    af[kk8] = *(const s16x8*)(Abf + d * 256 + kk8 * 32 + g * 8);
  const float bd = bias[d];

  const float* xbase = X + (long)b * Cn * HWn;
  float* obase = out + (long)b * Cn * HWn;
  float vx[16];

#define A_LOADS(CH)                                                           \
  {                                                                           \
    const int s0_ = (CH) * 64;                                                \
    _Pragma("unroll")                                                         \
    for (int p4 = 0; p4 < 4; ++p4) {                                          \
      const int c4_ = p4 * 16 + w;                                            \
      const float* xp_ = xbase + (long)(c4_ * 4) * HWn + s0_ + l;             \
      vx[p4 * 4 + 0] = xp_[0];                                                \
      vx[p4 * 4 + 1] = xp_[HWn];                                              \
      vx[p4 * 4 + 2] = xp_[2 * HWn];                                          \
      vx[p4 * 4 + 3] = xp_[3 * HWn];                                          \
    }                                                                         \
  }

#define A_CVTWR(BUF)                                                          \
  {                                                                           \
    _Pragma("unroll")                                                         \
    for (int p4 = 0; p4 < 4; ++p4) {                                          \
      const int c4_ = p4 * 16 + w;                                            \
      uint2 hh;                                                               \
      hh.x = cvt_pk_bf16(vx[p4 * 4 + 0], vx[p4 * 4 + 1]);                     \
      hh.y = cvt_pk_bf16(vx[p4 * 4 + 2], vx[p4 * 4 + 3]);                     \
      *(uint2*)(&lds[BUF][0] + ((l * 256 + c4_ * 4) ^ ((l & 7) << 3))) = hh;  \
    }                                                                         \
  }

  A_LOADS(ch0);
  A_CVTWR(0);
  __syncthreads();

  for (int ch = ch0; ch < ch1; ++ch) {
    const int cur = (ch - ch0) & 1;
    if (ch + 1 < ch1) A_LOADS(ch + 1);

    const unsigned short* tile = &lds[cur][0];
    f32x4 acc[4];
#pragma unroll
    for (int st = 0; st < 4; ++st) acc[st] = (f32x4){0.f, 0.f, 0.f, 0.f};
#pragma unroll
    for (int kk8 = 0; kk8 < 8; ++kk8) {
#pragma unroll
      for (int st = 0; st < 4; ++st) {
        const s16x8 xf = *(const s16x8*)(tile + (((st * 16 + a) * 256 + kk8 * 32 + g * 8) ^ ((a & 7) << 3)));
        acc[st] = __builtin_amdgcn_mfma_f32_16x16x32_bf16(xf, af[kk8], acc[st], 0, 0, 0);
      }
    }
    const int s0 = ch * 64;
#pragma unroll
    for (int st = 0; st < 4; ++st) {
      const f32x4 o = acc[st] - bd;
      __builtin_nontemporal_store(o, (f32x4*)(obase + (long)d * HWn + s0 + st * 16 + 4 * g));
    }

    if (ch + 1 < ch1) A_CVTWR(cur ^ 1);
    __syncthreads();
  }
#undef A_LOADS
#undef A_CVTWR
}

// ---------------------------------------------------------------------------
extern "C" void kernel_launch(void* const* d_in, const int* in_sizes, int n_in,
                              void* d_out, int out_size, void* d_ws, size_t ws_size,
                              hipStream_t stream) {
  const float* X = (const float*)d_in[0];
  const float* rot = (const float*)d_in[1];
  float* out = (float*)d_out;

  auto need = [](int np) -> size_t {
    return (size_t)4 * ((size_t)np * 65536 + (size_t)np * 256 + (size_t)np
                        + 3 * 65536 + 256 + 16 + 256)
         + (size_t)2 * 65536;
  };
  int nparts = 128;
  while (nparts > 4 && need(nparts) > ws_size) nparts >>= 1;

  float* w = (float*)d_ws;
  float* Gp = w;       w += (size_t)nparts * 65536;
  float* Sp = w;       w += (size_t)nparts * 256;
  float* Dp = w;       w += (size_t)nparts;
  float* Sigma = w;    w += 65536;
  float* P0 = w;       w += 65536;
  float* P1 = w;       w += 65536;
  float* meansum = w;  w += 256;
  float* scal = w;     w += 16;
  float* bias = w;     w += 256;
  unsigned short* Abf = (unsigned short*)w;

  k_gram<<<dim3(nparts), dim3(1024), 0, stream>>>(X, Gp, Sp, Dp, nparts);
  k_reduce<<<dim3(256), dim3(1024), 0, stream>>>(Gp, Sp, Dp, Sigma, P1, meansum, scal, nparts);
  float* ps = P1;   // holds P1 after k_reduce
  float* pd = P0;
  for (int i = 0; i < 8; ++i) {   // P2..P9
    k_ns<<<dim3(64), dim3(1024), 0, stream>>>(ps, pd, Sigma, scal);
    float* tmp = ps; ps = pd; pd = tmp;
  }
  // last NS step (P10) fused with A = sqrt(rTr)*rot*P10 and bias
  k_ns_makeA<<<dim3(64), dim3(1024), 0, stream>>>(ps, Sigma, rot, scal, meansum, Abf, bias);
  k_apply<<<dim3(512), dim3(1024), 0, stream>>>(X, Abf, bias, out);
}

// Round 8
// 277.616 us; speedup vs baseline: 1.7377x; 1.0266x over previous
//
#include <hip/hip_runtime.h>
#include <math.h>

#define HWn   3136
#define Cn    256
#define KCPB  49          // 3136/64 k-chunks per batch image
#define NCHUNK 3136       // 64 batches * 49 chunks
#define INV_M (1.0f/200704.0f)
#define EPSc  1e-5f

typedef __attribute__((ext_vector_type(4))) float f32x4;
typedef __attribute__((ext_vector_type(8))) short s16x8;
typedef __attribute__((ext_vector_type(4))) unsigned short u16x4;

static __device__ __forceinline__ unsigned short f2bf(float f) {
  unsigned int u = __builtin_bit_cast(unsigned int, f);
  u = (u + 0x7fffu + ((u >> 16) & 1u)) >> 16;   // RNE
  return (unsigned short)u;
}

// HW packed f32x2 -> bf16x2 (RNE).
static __device__ __forceinline__ unsigned int cvt_pk_bf16(float lo, float hi) {
  unsigned int r;
  asm("v_cvt_pk_bf16_f32 %0, %1, %2" : "=v"(r) : "v"(lo), "v"(hi));
  return r;
}

// ---------------------------------------------------------------------------
// Kernel 1: partial Gram + per-part channel sums (Sp) + Gram-diag partial (Dp).
// 512 threads = 8 waves; each wave owns a 32-row output strip (2x16-row
// blocks) so each fj LDS read feeds 2 MFMAs: LDS reads 288KB/tile vs 544KB
// for the 16-wave variant. nparts=256 -> one block per CU.
// Double-buffered LDS, T14 split. Gp stores nontemporal.
// ---------------------------------------------------------------------------
__global__ __launch_bounds__(512) void k_gram(const float* __restrict__ X,
                                              float* __restrict__ Gp,
                                              float* __restrict__ Sp,
                                              float* __restrict__ Dp,
                                              int nparts) {
  __shared__ __align__(16) unsigned short lds[2][256 * 64];
  const int t = threadIdx.x, p = blockIdx.x;
  const int w = t >> 6, l = t & 63, a = l & 15, g = l >> 4;
  const int swzA = (a & 7) << 3;
  const int crow = t >> 1, h = t & 1;       // staging: row crow, k-half h

  f32x4 acc[2][16];
#pragma unroll
  for (int rb = 0; rb < 2; ++rb)
#pragma unroll
    for (int j = 0; j < 16; ++j) acc[rb][j] = (f32x4){0.f, 0.f, 0.f, 0.f};
  float sumc = 0.f;
  float vx[32];

  const int start = (int)(((long)NCHUNK * p) / nparts);
  const int end   = (int)(((long)NCHUNK * (p + 1)) / nparts);

#define G_LOADS(CH)                                                           \
  {                                                                           \
    const int b_ = (CH) / KCPB, kc_ = (CH) % KCPB;                            \
    const float* xb_ = X + (long)b_ * Cn * HWn + kc_ * 64                     \
                         + (long)crow * HWn + h * 32;                         \
    _Pragma("unroll")                                                         \
    for (int q = 0; q < 8; ++q) {                                             \
      const float4 v = *(const float4*)(xb_ + q * 4);                         \
      vx[q * 4 + 0] = v.x; vx[q * 4 + 1] = v.y;                               \
      vx[q * 4 + 2] = v.z; vx[q * 4 + 3] = v.w;                               \
    }                                                                         \
  }

#define G_CVTWR(BUF)                                                          \
  {                                                                           \
    float s_ = 0.f;                                                           \
    _Pragma("unroll")                                                         \
    for (int q = 0; q < 8; ++q) {                                             \
      s_ += (vx[q * 4 + 0] + vx[q * 4 + 1]) + (vx[q * 4 + 2] + vx[q * 4 + 3]); \
      uint2 hh;                                                               \
      hh.x = cvt_pk_bf16(vx[q * 4 + 0], vx[q * 4 + 1]);                       \
      hh.y = cvt_pk_bf16(vx[q * 4 + 2], vx[q * 4 + 3]);                       \
      *(uint2*)(&lds[BUF][0] +                                                \
          ((crow * 64 + h * 32 + q * 4) ^ ((crow & 7) << 3))) = hh;           \
    }                                                                         \
    sumc += s_;                                                               \
  }

  G_LOADS(start);
  G_CVTWR(0);
  __syncthreads();

  for (int ch = start; ch < end; ++ch) {
    const int cur = (ch - start) & 1;
    if (ch + 1 < end) G_LOADS(ch + 1);
    const unsigned short* tile = &lds[cur][0];
    // A fragments for this wave's 2 row-blocks (rows 32w..32w+31)
    s16x8 fw[2][2];
#pragma unroll
    for (int rb = 0; rb < 2; ++rb)
#pragma unroll
      for (int kk2 = 0; kk2 < 2; ++kk2)
        fw[rb][kk2] = *(const s16x8*)(tile +
            ((((2 * w + rb) * 16 + a) * 64 + kk2 * 32 + g * 8) ^ swzA));
#pragma unroll
    for (int j = 0; j < 16; ++j) {
      const s16x8 fj0 = *(const s16x8*)(tile + (((j * 16 + a) * 64 + 0  + g * 8) ^ swzA));
      const s16x8 fj1 = *(const s16x8*)(tile + (((j * 16 + a) * 64 + 32 + g * 8) ^ swzA));
      acc[0][j] = __builtin_amdgcn_mfma_f32_16x16x32_bf16(fw[0][0], fj0, acc[0][j], 0, 0, 0);
      acc[0][j] = __builtin_amdgcn_mfma_f32_16x16x32_bf16(fw[0][1], fj1, acc[0][j], 0, 0, 0);
      acc[1][j] = __builtin_amdgcn_mfma_f32_16x16x32_bf16(fw[1][0], fj0, acc[1][j], 0, 0, 0);
      acc[1][j] = __builtin_amdgcn_mfma_f32_16x16x32_bf16(fw[1][1], fj1, acc[1][j], 0, 0, 0);
    }
    if (ch + 1 < end) G_CVTWR(cur ^ 1);
    __syncthreads();
  }
#undef G_LOADS
#undef G_CVTWR

  // ---- write partial Gram (nontemporal; read once by k_reduce) ----
  // row = 32w + 16rb + 4g + r, col = 16j + a
  float* gout = Gp + (long)p * 65536;
#pragma unroll
  for (int rb = 0; rb < 2; ++rb)
#pragma unroll
    for (int j = 0; j < 16; ++j)
#pragma unroll
      for (int r = 0; r < 4; ++r)
        __builtin_nontemporal_store(acc[rb][j][r],
            gout + (32 * w + 16 * rb + 4 * g + r) * 256 + 16 * j + a);

  // ---- channel sums: combine the 2 stage-threads per row ----
  {
    const float so = __shfl_xor(sumc, 1);
    if ((t & 1) == 0) Sp[(long)p * 256 + crow] = sumc + so;
  }

  // ---- Gram diagonal partial (row==col elements live in wave w's acc) ----
  {
    float dsum = 0.f;
#pragma unroll
    for (int rb = 0; rb < 2; ++rb)
#pragma unroll
      for (int jj = 0; jj < 16; ++jj)
        if (jj == 2 * w + rb)
#pragma unroll
          for (int r = 0; r < 4; ++r)
            if (a == 4 * g + r) dsum += acc[rb][jj][r];
#pragma unroll
    for (int off = 1; off < 64; off <<= 1) dsum += __shfl_xor(dsum, off);
    float* lf = (float*)lds;
    __syncthreads();
    if (l == 0) lf[w] = dsum;
    __syncthreads();
    if (t == 0) {
      float d = 0.f;
#pragma unroll
      for (int ww = 0; ww < 8; ++ww) d += lf[ww];
      Dp[p] = d;
    }
  }
}

// ---------------------------------------------------------------------------
// Kernel 2: reduce partials -> Sigma row per block; fused iteration-0:
// every block computes trace (identical order) -> rTr -> P1 row.
// ---------------------------------------------------------------------------
__global__ __launch_bounds__(1024) void k_reduce(const float* __restrict__ Gp,
                                                 const float* __restrict__ Sp,
                                                 const float* __restrict__ Dp,
                                                 float* __restrict__ Sigma,
                                                 float* __restrict__ P1,
                                                 float* __restrict__ meansum,
                                                 float* __restrict__ scal,
                                                 int nparts) {
  __shared__ float redA[4][256];
  __shared__ float msh[256];
  __shared__ float scrD[256];
  __shared__ float scrM[256];
  __shared__ __align__(16) float redB[16][256];
  const int t = threadIdx.x, j = blockIdx.x;
  const int c = t & 255, g = t >> 8;

  // ---- Phase A: channel sums ----
  {
    float s = 0.f;
    const int pa0 = (nparts * g) >> 2, pa1 = (nparts * (g + 1)) >> 2;
    for (int p = pa0; p < pa1; ++p) s += Sp[(long)p * 256 + c];
    redA[g][c] = s;
  }
  __syncthreads();
  if (g == 0) msh[c] = (redA[0][c] + redA[1][c]) + (redA[2][c] + redA[3][c]);
  __syncthreads();

  // ---- trace inputs: Gram-diag partials + mean^2 ----
  if (t < 256) {
    scrD[t] = (t < nparts) ? Dp[t] : 0.f;
    const float mc = msh[t] * INV_M;
    scrM[t] = mc * mc;
  }
  __syncthreads();
  for (int st = 128; st > 0; st >>= 1) {
    if (t < st) { scrD[t] += scrD[t + st]; scrM[t] += scrM[t + st]; }
    __syncthreads();
  }
  const float tr = scrD[0] * INV_M - scrM[0] + 256.f * EPSc;
  const float rTr = 1.0f / tr;

  // ---- Phase B: Gram column reduction, nontemporal float4 slabs ----
  {
    const int c4 = (t & 63) * 4, sl = t >> 6;
    const int pb0 = (nparts * sl) >> 4, pb1 = (nparts * (sl + 1)) >> 4;
    const float* gp = Gp + (long)pb0 * 65536 + (long)j * 256 + c4;
    f32x4 s4 = (f32x4){0.f, 0.f, 0.f, 0.f};
    for (int p = pb0; p < pb1; ++p) {
      s4 += __builtin_nontemporal_load((const f32x4*)gp);
      gp += 65536;
    }
    *(f32x4*)&redB[sl][c4] = s4;
  }
  __syncthreads();

  if (t < 256) {
    float t0 = 0.f, t1 = 0.f;
#pragma unroll
    for (int sl = 0; sl < 16; sl += 2) { t0 += redB[sl][t]; t1 += redB[sl + 1][t]; }
    const float tot = t0 + t1;
    const float mc = msh[t] * INV_M;
    const float mj = msh[j] * INV_M;
    const float sig = tot * INV_M - mj * mc + ((j == t) ? EPSc : 0.f);
    Sigma[(long)j * 256 + t] = sig;
    // fused iteration 0 (P = I):  P1 = 1.5 I - 0.5 rTr Sigma
    P1[(long)j * 256 + t] = ((j == t) ? 1.5f : 0.f) - 0.5f * rTr * sig;
    if (j == 0) {
      meansum[t] = msh[t];
      if (t == 0) { scal[0] = tr; scal[1] = rTr; scal[2] = sqrtf(rTr); }
    }
  }
}

// ---------------------------------------------------------------------------
// Kernel 3 (x8): one Newton-Schulz step, fp32.
// ---------------------------------------------------------------------------
__global__ __launch_bounds__(1024) void k_ns(const float* __restrict__ Ps,
                                             float* __restrict__ Pd,
                                             const float* __restrict__ Sig,
                                             const float* __restrict__ scal) {
  __shared__ __align__(16) float PT[256][4];       // A-panel transposed [k][r]
  __shared__ __align__(16) float red[4][256][4];   // [kh][c][r]
  const int t = threadIdx.x, c = t & 255, kh = t >> 8, k0 = kh * 64;
  const int r0 = blockIdx.x * 4;

  PT[c][kh] = Ps[(r0 + kh) * 256 + c];
  __syncthreads();

  f32x4 acc;

#define NS_PHASE(BPTR)                                                        \
  {                                                                           \
    acc = (f32x4){0.f, 0.f, 0.f, 0.f};                                        \
    const float* Bb = (BPTR) + (long)k0 * 256 + c;                            \
    _Pragma("unroll 8")                                                       \
    for (int kk = 0; kk < 64; ++kk) {                                         \
      const float b = Bb[(long)kk * 256];                                     \
      const f32x4 a4 = *(const f32x4*)&PT[k0 + kk][0];                        \
      acc += a4 * b;                                                          \
    }                                                                         \
    *(f32x4*)&red[kh][c][0] = acc;                                            \
    __syncthreads();                                                          \
  }

#define NS_COMBINE()                                                          \
  {                                                                           \
    const f32x4 vs = (*(const f32x4*)&red[0][c][0] + *(const f32x4*)&red[1][c][0]) \
                   + (*(const f32x4*)&red[2][c][0] + *(const f32x4*)&red[3][c][0]); \
    if (kh == 0) *(f32x4*)&PT[c][0] = vs;                                     \
    __syncthreads();                                                          \
  }

  NS_PHASE(Ps);    // t1 = panel(P) * P
  NS_COMBINE();
  NS_PHASE(Ps);    // t2 = t1 * P
  NS_COMBINE();
  NS_PHASE(Sig);   // t3 = t2 * Sigma

  const float rTr = scal[1];
  const float t3 = ((red[0][c][kh] + red[1][c][kh]) + (red[2][c][kh] + red[3][c][kh]));
  const float pr = Ps[(r0 + kh) * 256 + c];
  Pd[(r0 + kh) * 256 + c] = 1.5f * pr - 0.5f * rTr * t3;
}

// ---------------------------------------------------------------------------
// Kernel 4: fused last NS step + makeA.
// ---------------------------------------------------------------------------
__global__ __launch_bounds__(1024) void k_ns_makeA(const float* __restrict__ Ps,
                                                   const float* __restrict__ Sig,
                                                   const float* __restrict__ rot,
                                                   const float* __restrict__ scal,
                                                   const float* __restrict__ meansum,
                                                   unsigned short* __restrict__ Abf,
                                                   float* __restrict__ bias) {
  __shared__ __align__(16) float PT[256][4];
  __shared__ __align__(16) float red[4][256][4];
  __shared__ float Tw[4][256];
  const int t = threadIdx.x, c = t & 255, kh = t >> 8, k0 = kh * 64;
  const int r0 = blockIdx.x * 4;

  PT[c][kh] = rot[(r0 + kh) * 256 + c];
  __syncthreads();

  f32x4 acc;

  NS_PHASE(Ps);    // T1 = rot_panel * P9
  NS_COMBINE();
  const float t1 = PT[c][kh];          // own element of T1 (row kh, col c)
  NS_PHASE(Ps);    // T2 = T1 * P9
  NS_COMBINE();
  NS_PHASE(Ps);    // T3 = T2 * P9
  NS_COMBINE();
  NS_PHASE(Sig);   // T4 = T3 * Sigma

  const float rTr = scal[1];
  const float sq = scal[2];
  const float t4 = (red[0][c][kh] + red[1][c][kh]) + (red[2][c][kh] + red[3][c][kh]);
  const float av = sq * (1.5f * t1 - 0.5f * rTr * t4);
  Abf[(r0 + kh) * 256 + c] = f2bf(av);
  const float mc = meansum[c] * INV_M;
  Tw[kh][c] = av * mc;
  __syncthreads();
  for (int st = 128; st > 0; st >>= 1) {
    if (c < st) Tw[kh][c] += Tw[kh][c + st];
    __syncthreads();
  }
  if (c == 0) bias[r0 + kh] = Tw[kh][0];
#undef NS_PHASE
#undef NS_COMBINE
}

// ---------------------------------------------------------------------------
// Kernel 5: out = A*x - bias. 512 blocks (64 b x 8 strips of 6-7 chunks).
// ---------------------------------------------------------------------------
__global__ __launch_bounds__(1024) void k_apply(const float* __restrict__ X,
                                                const unsigned short* __restrict__ Abf,
                                                const float* __restrict__ bias,
                                                float* __restrict__ out) {
  __shared__ __align__(16) unsigned short lds[2][64 * 256];
  const int t = threadIdx.x, w = t >> 6, l = t & 63, a = l & 15, g = l >> 4;
  const int bid = blockIdx.x;
  const int b = bid >> 3, strip = bid & 7;
  const int ch0 = (49 * strip) >> 3, ch1 = (49 * (strip + 1)) >> 3;

  const int d = 16 * w + a;
  s16x8 af[8];
#pragma unroll
  for (int kk8 = 0; kk8 < 8; ++kk8)
    af[kk8] = *(const s16x8*)(Abf + d * 256 + kk8 * 32 + g * 8);
  const float bd = bias[d];

  const float* xbase = X + (long)b * Cn * HWn;
  float* obase = out + (long)b * Cn * HWn;
  float vx[16];

#define A_LOADS(CH)                                                           \
  {                                                                           \
    const int s0_ = (CH) * 64;                                                \
    _Pragma("unroll")                                                         \
    for (int p4 = 0; p4 < 4; ++p4) {                                          \
      const int c4_ = p4 * 16 + w;                                            \
      const float* xp_ = xbase + (long)(c4_ * 4) * HWn + s0_ + l;             \
      vx[p4 * 4 + 0] = xp_[0];                                                \
      vx[p4 * 4 + 1] = xp_[HWn];                                              \
      vx[p4 * 4 + 2] = xp_[2 * HWn];                                          \
      vx[p4 * 4 + 3] = xp_[3 * HWn];                                          \
    }                                                                         \
  }

#define A_CVTWR(BUF)                                                          \
  {                                                                           \
    _Pragma("unroll")                                                         \
    for (int p4 = 0; p4 < 4; ++p4) {                                          \
      const int c4_ = p4 * 16 + w;                                            \
      uint2 hh;                                                               \
      hh.x = cvt_pk_bf16(vx[p4 * 4 + 0], vx[p4 * 4 + 1]);                     \
      hh.y = cvt_pk_bf16(vx[p4 * 4 + 2], vx[p4 * 4 + 3]);                     \
      *(uint2*)(&lds[BUF][0] + ((l * 256 + c4_ * 4) ^ ((l & 7) << 3))) = hh;  \
    }                                                                         \
  }

  A_LOADS(ch0);
  A_CVTWR(0);
  __syncthreads();

  for (int ch = ch0; ch < ch1; ++ch) {
    const int cur = (ch - ch0) & 1;
    if (ch + 1 < ch1) A_LOADS(ch + 1);

    const unsigned short* tile = &lds[cur][0];
    f32x4 acc[4];
#pragma unroll
    for (int st = 0; st < 4; ++st) acc[st] = (f32x4){0.f, 0.f, 0.f, 0.f};
#pragma unroll
    for (int kk8 = 0; kk8 < 8; ++kk8) {
#pragma unroll
      for (int st = 0; st < 4; ++st) {
        const s16x8 xf = *(const s16x8*)(tile + (((st * 16 + a) * 256 + kk8 * 32 + g * 8) ^ ((a & 7) << 3)));
        acc[st] = __builtin_amdgcn_mfma_f32_16x16x32_bf16(xf, af[kk8], acc[st], 0, 0, 0);
      }
    }
    const int s0 = ch * 64;
#pragma unroll
    for (int st = 0; st < 4; ++st) {
      const f32x4 o = acc[st] - bd;
      __builtin_nontemporal_store(o, (f32x4*)(obase + (long)d * HWn + s0 + st * 16 + 4 * g));
    }

    if (ch + 1 < ch1) A_CVTWR(cur ^ 1);
    __syncthreads();
  }
#undef A_LOADS
#undef A_CVTWR
}

// ---------------------------------------------------------------------------
extern "C" void kernel_launch(void* const* d_in, const int* in_sizes, int n_in,
                              void* d_out, int out_size, void* d_ws, size_t ws_size,
                              hipStream_t stream) {
  const float* X = (const float*)d_in[0];
  const float* rot = (const float*)d_in[1];
  float* out = (float*)d_out;

  auto need = [](int np) -> size_t {
    return (size_t)4 * ((size_t)np * 65536 + (size_t)np * 256 + (size_t)np
                        + 3 * 65536 + 256 + 16 + 256)
         + (size_t)2 * 65536;
  };
  int nparts = 256;
  while (nparts > 4 && need(nparts) > ws_size) nparts >>= 1;

  float* w = (float*)d_ws;
  float* Gp = w;       w += (size_t)nparts * 65536;
  float* Sp = w;       w += (size_t)nparts * 256;
  float* Dp = w;       w += (size_t)nparts;
  float* Sigma = w;    w += 65536;
  float* P0 = w;       w += 65536;
  float* P1 = w;       w += 65536;
  float* meansum = w;  w += 256;
  float* scal = w;     w += 16;
  float* bias = w;     w += 256;
  unsigned short* Abf = (unsigned short*)w;

  k_gram<<<dim3(nparts), dim3(512), 0, stream>>>(X, Gp, Sp, Dp, nparts);
  k_reduce<<<dim3(256), dim3(1024), 0, stream>>>(Gp, Sp, Dp, Sigma, P1, meansum, scal, nparts);
  float* ps = P1;   // holds P1 after k_reduce
  float* pd = P0;
  for (int i = 0; i < 8; ++i) {   // P2..P9
    k_ns<<<dim3(64), dim3(1024), 0, stream>>>(ps, pd, Sigma, scal);
    float* tmp = ps; ps = pd; pd = tmp;
  }
  // last NS step (P10) fused with A = sqrt(rTr)*rot*P10 and bias
  k_ns_makeA<<<dim3(64), dim3(1024), 0, stream>>>(ps, Sigma, rot, scal, meansum, Abf, bias);
  k_apply<<<dim3(512), dim3(1024), 0, stream>>>(X, Abf, bias, out);
}

// Round 9
// 273.185 us; speedup vs baseline: 1.7659x; 1.0162x over previous
//
#include <hip/hip_runtime.h>
#include <math.h>

#define HWn   3136
#define Cn    256
#define KCPB  49          // 3136/64 k-chunks per batch image
#define NCHUNK 3136       // 64 batches * 49 chunks
#define INV_M (1.0f/200704.0f)
#define EPSc  1e-5f

typedef __attribute__((ext_vector_type(4))) float f32x4;
typedef __attribute__((ext_vector_type(8))) short s16x8;
typedef __attribute__((ext_vector_type(4))) unsigned short u16x4;

static __device__ __forceinline__ unsigned short f2bf(float f) {
  unsigned int u = __builtin_bit_cast(unsigned int, f);
  u = (u + 0x7fffu + ((u >> 16) & 1u)) >> 16;   // RNE
  return (unsigned short)u;
}

// HW packed f32x2 -> bf16x2 (RNE).
static __device__ __forceinline__ unsigned int cvt_pk_bf16(float lo, float hi) {
  unsigned int r;
  asm("v_cvt_pk_bf16_f32 %0, %1, %2" : "=v"(r) : "v"(lo), "v"(hi));
  return r;
}

// ---------------------------------------------------------------------------
// Kernel 1: partial Gram, UPPER-TRIANGLE tiles only (Gram is symmetric):
// wave w owns row-blocks {w, 15-w} (16 rows each), computes col-blocks j>=R.
// Balanced: 17 tile-MFMAs (x2 k-halves) per wave. Gp traffic 64->34 MB.
// Channel sums + Gram-diag exported via float atomics (meanacc pre-zeroed).
// Double-buffered LDS, T14 split. Gp stores nontemporal.
// ---------------------------------------------------------------------------
__global__ __launch_bounds__(512) void k_gram(const float* __restrict__ X,
                                              float* __restrict__ Gp,
                                              float* __restrict__ meanacc,
                                              float* __restrict__ gdt,
                                              int nparts) {
  __shared__ __align__(16) unsigned short lds[2][256 * 64];
  const int t = threadIdx.x, p = blockIdx.x;
  const int w = t >> 6, l = t & 63, a = l & 15, g = l >> 4;
  const int swzA = (a & 7) << 3;
  const int crow = t >> 1, h = t & 1;       // staging: row crow, k-half h
  const int R0 = w, R1 = 15 - w;            // this wave's two row-blocks

  f32x4 acc[2][16];
#pragma unroll
  for (int rb = 0; rb < 2; ++rb)
#pragma unroll
    for (int j = 0; j < 16; ++j) acc[rb][j] = (f32x4){0.f, 0.f, 0.f, 0.f};
  float sumc = 0.f;
  float vx[32];

  const int start = (int)(((long)NCHUNK * p) / nparts);
  const int end   = (int)(((long)NCHUNK * (p + 1)) / nparts);

#define G_LOADS(CH)                                                           \
  {                                                                           \
    const int b_ = (CH) / KCPB, kc_ = (CH) % KCPB;                            \
    const float* xb_ = X + (long)b_ * Cn * HWn + kc_ * 64                     \
                         + (long)crow * HWn + h * 32;                         \
    _Pragma("unroll")                                                         \
    for (int q = 0; q < 8; ++q) {                                             \
      const float4 v = *(const float4*)(xb_ + q * 4);                         \
      vx[q * 4 + 0] = v.x; vx[q * 4 + 1] = v.y;                               \
      vx[q * 4 + 2] = v.z; vx[q * 4 + 3] = v.w;                               \
    }                                                                         \
  }

#define G_CVTWR(BUF)                                                          \
  {                                                                           \
    float s_ = 0.f;                                                           \
    _Pragma("unroll")                                                         \
    for (int q = 0; q < 8; ++q) {                                             \
      s_ += (vx[q * 4 + 0] + vx[q * 4 + 1]) + (vx[q * 4 + 2] + vx[q * 4 + 3]); \
      uint2 hh;                                                               \
      hh.x = cvt_pk_bf16(vx[q * 4 + 0], vx[q * 4 + 1]);                       \
      hh.y = cvt_pk_bf16(vx[q * 4 + 2], vx[q * 4 + 3]);                       \
      *(uint2*)(&lds[BUF][0] +                                                \
          ((crow * 64 + h * 32 + q * 4) ^ ((crow & 7) << 3))) = hh;           \
    }                                                                         \
    sumc += s_;                                                               \
  }

  G_LOADS(start);
  G_CVTWR(0);
  __syncthreads();

  for (int ch = start; ch < end; ++ch) {
    const int cur = (ch - start) & 1;
    if (ch + 1 < end) G_LOADS(ch + 1);
    const unsigned short* tile = &lds[cur][0];
    // A fragments for the two owned row-blocks
    s16x8 fw0[2], fw1[2];
#pragma unroll
    for (int kk2 = 0; kk2 < 2; ++kk2) {
      fw0[kk2] = *(const s16x8*)(tile + (((R0 * 16 + a) * 64 + kk2 * 32 + g * 8) ^ swzA));
      fw1[kk2] = *(const s16x8*)(tile + (((R1 * 16 + a) * 64 + kk2 * 32 + g * 8) ^ swzA));
    }
#pragma unroll
    for (int j = 0; j < 16; ++j) {
      if (j >= R0) {                                     // wave-uniform
        const s16x8 fj0 = *(const s16x8*)(tile + (((j * 16 + a) * 64 + 0  + g * 8) ^ swzA));
        const s16x8 fj1 = *(const s16x8*)(tile + (((j * 16 + a) * 64 + 32 + g * 8) ^ swzA));
        acc[0][j] = __builtin_amdgcn_mfma_f32_16x16x32_bf16(fw0[0], fj0, acc[0][j], 0, 0, 0);
        acc[0][j] = __builtin_amdgcn_mfma_f32_16x16x32_bf16(fw0[1], fj1, acc[0][j], 0, 0, 0);
        if (j >= R1) {                                   // wave-uniform
          acc[1][j] = __builtin_amdgcn_mfma_f32_16x16x32_bf16(fw1[0], fj0, acc[1][j], 0, 0, 0);
          acc[1][j] = __builtin_amdgcn_mfma_f32_16x16x32_bf16(fw1[1], fj1, acc[1][j], 0, 0, 0);
        }
      }
    }
    if (ch + 1 < end) G_CVTWR(cur ^ 1);
    __syncthreads();
  }
#undef G_LOADS
#undef G_CVTWR

  // ---- write partial Gram upper tiles (nontemporal) + extract diag ----
  // acc[0][j]: tile (R0, j) j>=R0 ; acc[1][j]: tile (R1, j) j>=R1.
  // element: row 16*R + 4g + r, col 16*j + a.
  float* gout = Gp + (long)p * 65536;
  float dsum = 0.f;
#pragma unroll
  for (int j = 0; j < 16; ++j) {
    if (j >= R0) {
#pragma unroll
      for (int r = 0; r < 4; ++r) {
        __builtin_nontemporal_store(acc[0][j][r],
            gout + (16 * R0 + 4 * g + r) * 256 + 16 * j + a);
        if (j == R0 && a == 4 * g + r) dsum += acc[0][j][r];
      }
    }
    if (j >= R1) {
#pragma unroll
      for (int r = 0; r < 4; ++r) {
        __builtin_nontemporal_store(acc[1][j][r],
            gout + (16 * R1 + 4 * g + r) * 256 + 16 * j + a);
        if (j == R1 && a == 4 * g + r) dsum += acc[1][j][r];
      }
    }
  }

  // ---- channel sums: combine the 2 stage-threads per row, atomic ----
  {
    const float so = __shfl_xor(sumc, 1);
    if (h == 0) atomicAdd(&meanacc[crow], sumc + so);
  }

  // ---- Gram diagonal: wave reduce + block reduce + one atomic ----
  {
#pragma unroll
    for (int off = 1; off < 64; off <<= 1) dsum += __shfl_xor(dsum, off);
    float* lf = (float*)lds;
    __syncthreads();
    if (l == 0) lf[w] = dsum;
    __syncthreads();
    if (t == 0) {
      float d = 0.f;
#pragma unroll
      for (int ww = 0; ww < 8; ++ww) d += lf[ww];
      atomicAdd(gdt, d);
    }
  }
}

// ---------------------------------------------------------------------------
// Kernel 2: per-tile reduction of upper-triangle Gp -> Sigma + P1 (mirrored).
// 136 blocks, one 16x16 tile each. Trace/rTr computed redundantly but
// deterministically (identical LDS tree in every block).
// ---------------------------------------------------------------------------
__global__ __launch_bounds__(1024) void k_sigma(const float* __restrict__ Gp,
                                                const float* __restrict__ meanacc,
                                                const float* __restrict__ gdt,
                                                float* __restrict__ Sigma,
                                                float* __restrict__ P1,
                                                float* __restrict__ scal,
                                                int nparts) {
  __shared__ float msh[256];
  __shared__ float mu2s[256];
  __shared__ __align__(16) float part[4][256];
  const int t = threadIdx.x;

  // tile decode: block b -> (i, j), i<=j
  int i = 0, rem = blockIdx.x;
  while (rem >= 16 - i) { rem -= 16 - i; ++i; }
  const int j = i + rem;

  if (t < 256) msh[t] = meanacc[t];
  __syncthreads();
  if (t < 256) { const float mc = msh[t] * INV_M; mu2s[t] = mc * mc; }
  __syncthreads();
  for (int st = 128; st > 0; st >>= 1) {
    if (t < st) mu2s[t] += mu2s[t + st];
    __syncthreads();
  }
  const float tr = gdt[0] * INV_M - mu2s[0] + 256.f * EPSc;
  const float rTr = 1.0f / tr;

  // ---- tile reduce over parts (4 p-slices) ----
  const int e = t & 255, sl = t >> 8;
  const int r_ = e >> 4, c_ = e & 15;
  const int psl = nparts >> 2;
  {
    const float* gp = Gp + (long)(sl * psl) * 65536 + (16 * i + r_) * 256 + 16 * j + c_;
    float s = 0.f;
    for (int p = 0; p < psl; ++p) {
      s += __builtin_nontemporal_load(gp);
      gp += 65536;
    }
    part[sl][e] = s;
  }
  __syncthreads();

  if (sl == 0) {
    const float gsum = (part[0][e] + part[1][e]) + (part[2][e] + part[3][e]);
    const int row = 16 * i + r_, col = 16 * j + c_;
    const float mur = msh[row] * INV_M;
    const float muc = msh[col] * INV_M;
    const float sig = gsum * INV_M - mur * muc + ((row == col) ? EPSc : 0.f);
    const float p1v = ((row == col) ? 1.5f : 0.f) - 0.5f * rTr * sig;
    Sigma[row * 256 + col] = sig;
    P1[row * 256 + col] = p1v;
    if (i != j) {                   // mirror (Sigma, P1 symmetric)
      Sigma[col * 256 + row] = sig;
      P1[col * 256 + row] = p1v;
    }
    if (blockIdx.x == 0 && e == 0) {
      scal[0] = tr; scal[1] = rTr; scal[2] = sqrtf(rTr);
    }
  }
}

// ---------------------------------------------------------------------------
// Kernel 3 (x8): one Newton-Schulz step, fp32.
// 64 blocks x 1024 threads: 4 rows/block, 256 cols, split-K x4.
// ---------------------------------------------------------------------------
__global__ __launch_bounds__(1024) void k_ns(const float* __restrict__ Ps,
                                             float* __restrict__ Pd,
                                             const float* __restrict__ Sig,
                                             const float* __restrict__ scal) {
  __shared__ __align__(16) float PT[256][4];       // A-panel transposed [k][r]
  __shared__ __align__(16) float red[4][256][4];   // [kh][c][r]
  const int t = threadIdx.x, c = t & 255, kh = t >> 8, k0 = kh * 64;
  const int r0 = blockIdx.x * 4;

  PT[c][kh] = Ps[(r0 + kh) * 256 + c];
  __syncthreads();

  f32x4 acc;

#define NS_PHASE(BPTR)                                                        \
  {                                                                           \
    acc = (f32x4){0.f, 0.f, 0.f, 0.f};                                        \
    const float* Bb = (BPTR) + (long)k0 * 256 + c;                            \
    _Pragma("unroll 8")                                                       \
    for (int kk = 0; kk < 64; ++kk) {                                         \
      const float b = Bb[(long)kk * 256];                                     \
      const f32x4 a4 = *(const f32x4*)&PT[k0 + kk][0];                        \
      acc += a4 * b;                                                          \
    }                                                                         \
    *(f32x4*)&red[kh][c][0] = acc;                                            \
    __syncthreads();                                                          \
  }

#define NS_COMBINE()                                                          \
  {                                                                           \
    const f32x4 vs = (*(const f32x4*)&red[0][c][0] + *(const f32x4*)&red[1][c][0]) \
                   + (*(const f32x4*)&red[2][c][0] + *(const f32x4*)&red[3][c][0]); \
    if (kh == 0) *(f32x4*)&PT[c][0] = vs;                                     \
    __syncthreads();                                                          \
  }

  NS_PHASE(Ps);    // t1 = panel(P) * P
  NS_COMBINE();
  NS_PHASE(Ps);    // t2 = t1 * P
  NS_COMBINE();
  NS_PHASE(Sig);   // t3 = t2 * Sigma

  const float rTr = scal[1];
  const float t3 = ((red[0][c][kh] + red[1][c][kh]) + (red[2][c][kh] + red[3][c][kh]));
  const float pr = Ps[(r0 + kh) * 256 + c];
  Pd[(r0 + kh) * 256 + c] = 1.5f * pr - 0.5f * rTr * t3;
}

// ---------------------------------------------------------------------------
// Kernel 4: fused last NS step + makeA.
// ---------------------------------------------------------------------------
__global__ __launch_bounds__(1024) void k_ns_makeA(const float* __restrict__ Ps,
                                                   const float* __restrict__ Sig,
                                                   const float* __restrict__ rot,
                                                   const float* __restrict__ scal,
                                                   const float* __restrict__ meanacc,
                                                   unsigned short* __restrict__ Abf,
                                                   float* __restrict__ bias) {
  __shared__ __align__(16) float PT[256][4];
  __shared__ __align__(16) float red[4][256][4];
  __shared__ float Tw[4][256];
  const int t = threadIdx.x, c = t & 255, kh = t >> 8, k0 = kh * 64;
  const int r0 = blockIdx.x * 4;

  PT[c][kh] = rot[(r0 + kh) * 256 + c];
  __syncthreads();

  f32x4 acc;

  NS_PHASE(Ps);    // T1 = rot_panel * P9
  NS_COMBINE();
  const float t1 = PT[c][kh];          // own element of T1 (row kh, col c)
  NS_PHASE(Ps);    // T2 = T1 * P9
  NS_COMBINE();
  NS_PHASE(Ps);    // T3 = T2 * P9
  NS_COMBINE();
  NS_PHASE(Sig);   // T4 = T3 * Sigma

  const float rTr = scal[1];
  const float sq = scal[2];
  const float t4 = (red[0][c][kh] + red[1][c][kh]) + (red[2][c][kh] + red[3][c][kh]);
  const float av = sq * (1.5f * t1 - 0.5f * rTr * t4);
  Abf[(r0 + kh) * 256 + c] = f2bf(av);
  const float mc = meanacc[c] * INV_M;
  Tw[kh][c] = av * mc;
  __syncthreads();
  for (int st = 128; st > 0; st >>= 1) {
    if (c < st) Tw[kh][c] += Tw[kh][c + st];
    __syncthreads();
  }
  if (c == 0) bias[r0 + kh] = Tw[kh][0];
#undef NS_PHASE
#undef NS_COMBINE
}

// ---------------------------------------------------------------------------
// Kernel 5: out = A*x - bias. 512 blocks (64 b x 8 strips of 6-7 chunks).
// Swapped MFMA operands -> D rows = s -> nontemporal float4 stores.
// ---------------------------------------------------------------------------
__global__ __launch_bounds__(1024) void k_apply(const float* __restrict__ X,
                                                const unsigned short* __restrict__ Abf,
                                                const float* __restrict__ bias,
                                                float* __restrict__ out) {
  __shared__ __align__(16) unsigned short lds[2][64 * 256];
  const int t = threadIdx.x, w = t >> 6, l = t & 63, a = l & 15, g = l >> 4;
  const int bid = blockIdx.x;
  const int b = bid >> 3, strip = bid & 7;
  const int ch0 = (49 * strip) >> 3, ch1 = (49 * (strip + 1)) >> 3;

  const int d = 16 * w + a;
  s16x8 af[8];
#pragma unroll
  for (int kk8 = 0; kk8 < 8; ++kk8)
    af[kk8] = *(const s16x8*)(Abf + d * 256 + kk8 * 32 + g * 8);
  const float bd = bias[d];

  const float* xbase = X + (long)b * Cn * HWn;
  float* obase = out + (long)b * Cn * HWn;
  float vx[16];

#define A_LOADS(CH)                                                           \
  {                                                                           \
    const int s0_ = (CH) * 64;                                                \
    _Pragma("unroll")                                                         \
    for (int p4 = 0; p4 < 4; ++p4) {                                          \
      const int c4_ = p4 * 16 + w;                                            \
      const float* xp_ = xbase + (long)(c4_ * 4) * HWn + s0_ + l;             \
      vx[p4 * 4 + 0] = xp_[0];                                                \
      vx[p4 * 4 + 1] = xp_[HWn];                                              \
      vx[p4 * 4 + 2] = xp_[2 * HWn];                                          \
      vx[p4 * 4 + 3] = xp_[3 * HWn];                                          \
    }                                                                         \
  }

#define A_CVTWR(BUF)                                                          \
  {                                                                           \
    _Pragma("unroll")                                                         \
    for (int p4 = 0; p4 < 4; ++p4) {                                          \
      const int c4_ = p4 * 16 + w;                                            \
      uint2 hh;                                                               \
      hh.x = cvt_pk_bf16(vx[p4 * 4 + 0], vx[p4 * 4 + 1]);                     \
      hh.y = cvt_pk_bf16(vx[p4 * 4 + 2], vx[p4 * 4 + 3]);                     \
      *(uint2*)(&lds[BUF][0] + ((l * 256 + c4_ * 4) ^ ((l & 7) << 3))) = hh;  \
    }                                                                         \
  }

  A_LOADS(ch0);
  A_CVTWR(0);
  __syncthreads();

  for (int ch = ch0; ch < ch1; ++ch) {
    const int cur = (ch - ch0) & 1;
    if (ch + 1 < ch1) A_LOADS(ch + 1);

    const unsigned short* tile = &lds[cur][0];
    f32x4 acc[4];
#pragma unroll
    for (int st = 0; st < 4; ++st) acc[st] = (f32x4){0.f, 0.f, 0.f, 0.f};
#pragma unroll
    for (int kk8 = 0; kk8 < 8; ++kk8) {
#pragma unroll
      for (int st = 0; st < 4; ++st) {
        const s16x8 xf = *(const s16x8*)(tile + (((st * 16 + a) * 256 + kk8 * 32 + g * 8) ^ ((a & 7) << 3)));
        acc[st] = __builtin_amdgcn_mfma_f32_16x16x32_bf16(xf, af[kk8], acc[st], 0, 0, 0);
      }
    }
    const int s0 = ch * 64;
#pragma unroll
    for (int st = 0; st < 4; ++st) {
      const f32x4 o = acc[st] - bd;
      __builtin_nontemporal_store(o, (f32x4*)(obase + (long)d * HWn + s0 + st * 16 + 4 * g));
    }

    if (ch + 1 < ch1) A_CVTWR(cur ^ 1);
    __syncthreads();
  }
#undef A_LOADS
#undef A_CVTWR
}

// ---------------------------------------------------------------------------
extern "C" void kernel_launch(void* const* d_in, const int* in_sizes, int n_in,
                              void* d_out, int out_size, void* d_ws, size_t ws_size,
                              hipStream_t stream) {
  const float* X = (const float*)d_in[0];
  const float* rot = (const float*)d_in[1];
  float* out = (float*)d_out;

  auto need = [](int np) -> size_t {
    return (size_t)4 * ((size_t)np * 65536 + 3 * 65536 + 256 + 16 + 16 + 256)
         + (size_t)2 * 65536;
  };
  int nparts = 256;
  while (nparts > 8 && need(nparts) > ws_size) nparts >>= 1;

  float* w = (float*)d_ws;
  float* Gp = w;       w += (size_t)nparts * 65536;
  float* Sigma = w;    w += 65536;
  float* P0 = w;       w += 65536;
  float* P1 = w;       w += 65536;
  float* meanacc = w;  w += 256;   // atomic channel sums
  float* gdt = w;      w += 16;    // atomic Gram-diag total
  float* scal = w;     w += 16;
  float* bias = w;     w += 256;
  unsigned short* Abf = (unsigned short*)w;

  // zero the atomic accumulators (meanacc + gdt contiguous)
  hipMemsetAsync(meanacc, 0, (256 + 16) * sizeof(float), stream);

  k_gram<<<dim3(nparts), dim3(512), 0, stream>>>(X, Gp, meanacc, gdt, nparts);
  k_sigma<<<dim3(136), dim3(1024), 0, stream>>>(Gp, meanacc, gdt, Sigma, P1, scal, nparts);
  float* ps = P1;   // holds P1 after k_sigma
  float* pd = P0;
  for (int i = 0; i < 8; ++i) {   // P2..P9
    k_ns<<<dim3(64), dim3(1024), 0, stream>>>(ps, pd, Sigma, scal);
    float* tmp = ps; ps = pd; pd = tmp;
  }
  // last NS step (P10) fused with A = sqrt(rTr)*rot*P10 and bias
  k_ns_makeA<<<dim3(64), dim3(1024), 0, stream>>>(ps, Sigma, rot, scal, meanacc, Abf, bias);
  k_apply<<<dim3(512), dim3(1024), 0, stream>>>(X, Abf, bias, out);
}